// Round 9
// baseline (223.450 us; speedup 1.0000x reference)
//
#include <hip/hip_runtime.h>

#define NUM_EMBED 1024
#define EMBED_DIM 256
#define SPATIAL 4096          // 64*64
#define NROWS 65536           // 16*4096
#define EMBED_ELEMS 16777216  // 16*256*4096
#define HMARGIN 0.05f         // margin on h = d2/2 scores (== 0.1 on d2)

typedef _Float16 half8 __attribute__((ext_vector_type(8)));
typedef float f32x4 __attribute__((ext_vector_type(4)));

__device__ __forceinline__ unsigned fkey(float f) {
  unsigned u = __float_as_uint(f);
  return (u & 0x80000000u) ? ~u : (u | 0x80000000u);
}

__device__ __forceinline__ void gll16(const _Float16* g, void* l) {
  __builtin_amdgcn_global_load_lds((const __attribute__((address_space(1))) void*)g,
                                   (__attribute__((address_space(3))) void*)l, 16, 0, 0);
}

#define UPD(V1, V2, I1, S, I)                            \
  { float _s = (S);                                      \
    if (_s < (V1)) { (V2) = (V1); (V1) = _s; (I1) = (I); } \
    else if (_s < (V2)) { (V2) = _s; } }

#define MERGE(V1A, V2A, I1A, V1B, V2B, I1B)                       \
  { if ((V1B) < (V1A)) { (V2A) = fminf((V1A), (V2B)); (V1A) = (V1B); (I1A) = (I1B); } \
    else { (V2A) = fminf((V2A), (V1B)); } }

// ---------------- init: used, flagcount, cnorm, cb16 (PERMUTED for k_score staging) ----------------
// cb16p half-index D = 8*gid, gid = c*1024 + i*256 + t  <-  source half-index
// S = c*8192 + (t&31)*256 + (t>>5)*8 + i*64  (so k_score's gll sources are
// thread-contiguous: one wave instruction = 1 KB contiguous).
__global__ __launch_bounds__(256) void k_init(const float* __restrict__ cb,
                                              int* __restrict__ used,
                                              int* __restrict__ flagcount,
                                              float* __restrict__ cnorm,
                                              _Float16* __restrict__ cb16) {
  int bid = blockIdx.x, tid = threadIdx.x;
  if (bid == 0) {
    used[tid] = 0; used[tid + 256] = 0; used[tid + 512] = 0; used[tid + 768] = 0;
    if (tid == 0) *flagcount = 0;
  } else if (bid <= 64) {
    int c = (bid - 1) * 16 + (tid >> 4);
    int l = tid & 15;
    const float4* p = (const float4*)(cb + c * EMBED_DIM + l * 16);
    float s = 0.f;
#pragma unroll
    for (int j = 0; j < 4; ++j) {
      float4 v = p[j];
      s += v.x * v.x + v.y * v.y + v.z * v.z + v.w * v.w;
    }
#pragma unroll
    for (int off = 1; off < 16; off <<= 1) s += __shfl_xor(s, off, 16);
    if (l == 0) cnorm[c] = s;
  } else {
    int gid = (bid - 65) * 256 + tid;  // 0..32767
    int c = gid >> 10;
    int rem = gid & 1023;
    int i = rem >> 8;
    int t = rem & 255;
    int S = c * 8192 + (t & 31) * 256 + (t >> 5) * 8 + i * 64;
    const float4* src = (const float4*)(cb + S);
    float4 a = src[0], b = src[1];
    half8 h;
    h[0] = (_Float16)a.x; h[1] = (_Float16)a.y; h[2] = (_Float16)a.z; h[3] = (_Float16)a.w;
    h[4] = (_Float16)b.x; h[5] = (_Float16)b.y; h[6] = (_Float16)b.z; h[7] = (_Float16)b.w;
    *(half8*)(cb16 + gid * 8) = h;
  }
}

// ---------------- fp16 MFMA screening, FAT WAVES (64 rows/wave) ----------------
// block: 256 rows = 4 waves x 64 rows; grid 256 (1 block/CU). Per chunk/wave:
// 64 MFMA vs 16 ds_read_b128 (4:1). X frags xf[8][4] in registers via 2-pass
// 32-row LDS transpose (separate 64KB scratch). Codebook: 2-deep 16KB ring,
// gll16 from PERMUTED cb16 (contiguous), vmcnt(0)+barrier, stage(c+1) after
// barrier (one-compute lookahead).
__global__ __launch_bounds__(256, 1) void k_score(const float* __restrict__ in,
                                                  const _Float16* __restrict__ cb16,
                                                  const float* __restrict__ cnorm,
                                                  float* __restrict__ out_idx,
                                                  int* __restrict__ idxi,
                                                  int* __restrict__ flagged,
                                                  int* __restrict__ flagcount,
                                                  int* __restrict__ used) {
  __shared__ _Float16 As[2][8192];   // 32 KB ring
  __shared__ _Float16 Sc[4][8192];   // 64 KB transpose scratch (16 KB/wave)
  __shared__ float cn_lds[1024];     // 4 KB, pre-scaled x0.5
  int tid = threadIdx.x;
  int lane = tid & 63;
  int wave = tid >> 6;
  int ln = lane & 15;
  int lg = lane >> 4;
  int r0 = blockIdx.x << 8;  // 256 rows/block
  const float* Ain = in + ((r0 >> 12) * (EMBED_DIM * SPATIAL)) + (r0 & 4095);

  // issue stage(chunk 0) NOW — latency hides under the transpose
  const _Float16* pc = cb16 + tid * 8;  // permuted: contiguous per wave instr
  char* AsB = (char*)As[0];
  int dsto = tid * 16;
#pragma unroll
  for (int i = 0; i < 4; ++i) gll16(pc + i * 2048, AsB + i * 4096 + dsto);

  // ---- X transpose: 2 passes x 32 rows through this wave's 16KB scratch ----
  half8 xf[8][4];
  {
    char* scratch = (char*)Sc[wave];
    int row = lane & 31;
    int h = lane >> 5;  // kc half: kc = h*16 + jj
#pragma unroll 1
    for (int p = 0; p < 2; ++p) {
      const float* p0 = Ain + wave * 64 + p * 32 + row;
#pragma unroll
      for (int jj = 0; jj < 16; ++jj) {
        int kc = h * 16 + jj;
        half8 hv;
#pragma unroll
        for (int q = 0; q < 8; ++q) hv[q] = (_Float16)p0[(kc * 8 + q) * SPATIAL];
        *(half8*)(scratch + kc * 512 + row * 16) = hv;
      }
      asm volatile("s_waitcnt lgkmcnt(0)" ::: "memory");
      __builtin_amdgcn_sched_barrier(0);
#pragma unroll
      for (int ks = 0; ks < 8; ++ks)
#pragma unroll
        for (int n2 = 0; n2 < 2; ++n2)
          xf[ks][p * 2 + n2] =
              *(const half8*)(scratch + (ks * 4 + lg) * 512 + (n2 * 16 + ln) * 16);
      asm volatile("s_waitcnt lgkmcnt(0)" ::: "memory");
      __builtin_amdgcn_sched_barrier(0);
    }
  }

  // cnorm*0.5 -> LDS
#pragma unroll
  for (int i = 0; i < 4; ++i) cn_lds[tid + 256 * i] = 0.5f * cnorm[tid + 256 * i];
  __syncthreads();  // cn ready; (scratch is separate, ring b0 untouched by others)

  float sv1[4] = {3e38f, 3e38f, 3e38f, 3e38f};
  float sv2[4] = {3e38f, 3e38f, 3e38f, 3e38f};
  int si1[4] = {0, 0, 0, 0};

#pragma unroll 1
  for (int c = 0; c < 32; ++c) {
    asm volatile("s_waitcnt vmcnt(0)" ::: "memory");  // chunk c landed
    __builtin_amdgcn_s_barrier();                     // all waves see it / done with other buf
    asm volatile("" ::: "memory");
    if (c < 31) {  // stage chunk c+1 into the buffer just freed
      char* dst = AsB + ((c + 1) & 1) * 16384;
      const _Float16* ps = pc + (c + 1) * 8192;
#pragma unroll
      for (int i = 0; i < 4; ++i) gll16(ps + i * 2048, dst + i * 4096 + dsto);
    }
    const char* Ac = AsB + (c & 1) * 16384;
    f32x4 acc[2][4] = {};
    __builtin_amdgcn_s_setprio(1);
#pragma unroll
    for (int ks = 0; ks < 8; ++ks) {
      half8 af0 = *(const half8*)(Ac + ks * 2048 + lg * 512 + ln * 16);
      half8 af1 = *(const half8*)(Ac + ks * 2048 + lg * 512 + 256 + ln * 16);
#pragma unroll
      for (int nf = 0; nf < 4; ++nf) {
        acc[0][nf] = __builtin_amdgcn_mfma_f32_16x16x32_f16(af0, xf[ks][nf], acc[0][nf], 0, 0, 0);
        acc[1][nf] = __builtin_amdgcn_mfma_f32_16x16x32_f16(af1, xf[ks][nf], acc[1][nf], 0, 0, 0);
      }
    }
    __builtin_amdgcn_s_setprio(0);
    // fold: h = 0.5*|c|^2 - x.c ; codes c*32 + mf*16 + lg*4 + r
    float cna[4], cnb[4];
    *(float4*)cna = *(const float4*)(cn_lds + c * 32 + lg * 4);
    *(float4*)cnb = *(const float4*)(cn_lds + c * 32 + 16 + lg * 4);
    int ib0 = c * 32 + lg * 4;
#pragma unroll
    for (int nf = 0; nf < 4; ++nf) {
      float v1a = cna[0] - acc[0][nf][0], v2a = 3e38f;
      int i1a = ib0;
      float v1b = cnb[0] - acc[1][nf][0], v2b = 3e38f;
      int i1b = ib0 + 16;
#pragma unroll
      for (int r = 1; r < 4; ++r) {
        UPD(v1a, v2a, i1a, cna[r] - acc[0][nf][r], ib0 + r);
        UPD(v1b, v2b, i1b, cnb[r] - acc[1][nf][r], ib0 + 16 + r);
      }
      MERGE(v1a, v2a, i1a, v1b, v2b, i1b);
      MERGE(sv1[nf], sv2[nf], si1[nf], v1a, v2a, i1a);
    }
  }

  // ---- merge the 4 lane-groups (same rows, disjoint codes); waves independent ----
#pragma unroll
  for (int nf = 0; nf < 4; ++nf) {
#pragma unroll
    for (int off = 16; off < 64; off <<= 1) {
      float ov1 = __shfl_xor(sv1[nf], off);
      float ov2 = __shfl_xor(sv2[nf], off);
      int oi = __shfl_xor(si1[nf], off);
      if (ov1 < sv1[nf]) { sv2[nf] = fminf(sv1[nf], ov2); sv1[nf] = ov1; si1[nf] = oi; }
      else { sv2[nf] = fminf(sv2[nf], ov1); }
    }
  }
  if (lg == 0) {
#pragma unroll
    for (int nf = 0; nf < 4; ++nf) {
      int grow = r0 + wave * 64 + nf * 16 + ln;
      out_idx[grow] = (float)si1[nf];
      idxi[grow] = si1[nf];
      if (sv2[nf] - sv1[nf] < HMARGIN) {
        int p = atomicAdd(flagcount, 1);
        flagged[p] = grow;
      } else {
        used[si1[nf]] = 1;  // final winner for unflagged rows (ties always flagged)
      }
    }
  }
}

// ---------------- exact fp32 re-rank: 1 flagged row per block, wave-per-code-slice ----------------
__global__ __launch_bounds__(256) void k_cleanup(const float* __restrict__ in,
                                                 const float* __restrict__ cb,
                                                 const float* __restrict__ cnorm,
                                                 const int* __restrict__ flagged,
                                                 const int* __restrict__ flagcount,
                                                 float* __restrict__ out_idx,
                                                 int* __restrict__ idxi,
                                                 int* __restrict__ used) {
  __shared__ unsigned long long red[4];
  int tid = threadIdx.x;
  int lane = tid & 63;
  int wave = tid >> 6;
  int nf = *flagcount;
  const float4* cb4 = (const float4*)cb;
  for (int fi = blockIdx.x; fi < nf; fi += 2048) {
    int row = flagged[fi];
    int b = row >> 12, s = row & 4095;
    const float* xp = in + b * (EMBED_DIM * SPATIAL) + s;
    float xk[4];
#pragma unroll
    for (int j = 0; j < 4; ++j) xk[j] = xp[(lane * 4 + j) * SPATIAL];
    unsigned long long best = ~0ull;
    int c0 = wave * 256;
#pragma unroll 4
    for (int cc = 0; cc < 256; ++cc) {
      int code = c0 + cc;
      float4 cv = cb4[code * 64 + lane];  // coalesced: 64 lanes x 16B
      float p = cv.x * xk[0] + cv.y * xk[1] + cv.z * xk[2] + cv.w * xk[3];
#pragma unroll
      for (int off = 1; off < 64; off <<= 1) p += __shfl_xor(p, off);
      float sc = cnorm[code] - 2.0f * p;
      unsigned long long k = ((unsigned long long)fkey(sc) << 32) | (unsigned)code;
      best = k < best ? k : best;
    }
    if (lane == 0) red[wave] = best;
    __syncthreads();
    if (tid == 0) {
      unsigned long long bb = red[0];
#pragma unroll
      for (int w = 1; w < 4; ++w) { unsigned long long o = red[w]; bb = o < bb ? o : bb; }
      int idx = (int)(bb & 0xffffffffull);
      out_idx[row] = (float)idx;
      idxi[row] = idx;
      used[idx] = 1;
    }
    __syncthreads();
  }
}

// ---------------- gather embed + MSE partial sums ----------------
__global__ __launch_bounds__(256) void k_gather(const float* __restrict__ in,
                                                const float* __restrict__ cb,
                                                const int* __restrict__ idxi,
                                                float* __restrict__ embed_out,
                                                double* __restrict__ partials) {
  int tid = threadIdx.x;
  float lsum = 0.f;
#pragma unroll
  for (int it = 0; it < 4; ++it) {
    int gid = (it * 4096 + blockIdx.x) * 256 + tid;
    int b = gid >> 18;
    int r = gid & 262143;
    int d = r >> 10;
    int s4 = r & 1023;
    int4 id4 = *(const int4*)(idxi + (b << 12) + (s4 << 2));
    int off = ((b * EMBED_DIM + d) << 12) + (s4 << 2);
    float4 x = *(const float4*)(in + off);
    float4 e;
    e.x = cb[id4.x * EMBED_DIM + d];
    e.y = cb[id4.y * EMBED_DIM + d];
    e.z = cb[id4.z * EMBED_DIM + d];
    e.w = cb[id4.w * EMBED_DIM + d];
    *(float4*)(embed_out + off) = e;
    float dx = e.x - x.x, dy = e.y - x.y, dz = e.z - x.z, dw = e.w - x.w;
    lsum += dx * dx + dy * dy + dz * dz + dw * dw;
  }
#pragma unroll
  for (int off = 1; off < 64; off <<= 1) lsum += __shfl_xor(lsum, off, 64);
  __shared__ float wsum[4];
  if ((tid & 63) == 0) wsum[tid >> 6] = lsum;
  __syncthreads();
  if (tid == 0)
    partials[blockIdx.x] = (double)(wsum[0] + wsum[1] + wsum[2] + wsum[3]);
}

// ---------------- tail: loss scalar + new_last_used ----------------
__global__ __launch_bounds__(256) void k_tail(const double* __restrict__ partials,
                                              const int* __restrict__ used,
                                              const int* __restrict__ last_used,
                                              float* __restrict__ out_loss,
                                              float* __restrict__ out_lu) {
  int tid = threadIdx.x;
  double s = 0.0;
  for (int i = tid; i < 4096; i += 256) s += partials[i];
#pragma unroll
  for (int off = 1; off < 64; off <<= 1) s += __shfl_xor(s, off, 64);
  __shared__ double sd[4];
  if ((tid & 63) == 0) sd[tid >> 6] = s;
  __syncthreads();
  if (tid == 0) {
    double total = sd[0] + sd[1] + sd[2] + sd[3];
    out_loss[0] = (float)(1.25 * total / (double)EMBED_ELEMS);
  }
  for (int i = tid; i < NUM_EMBED; i += 256)
    out_lu[i] = used[i] ? 0.0f : (float)(last_used[i] + 1);
}

extern "C" void kernel_launch(void* const* d_in, const int* in_sizes, int n_in,
                              void* d_out, int out_size, void* d_ws, size_t ws_size,
                              hipStream_t stream) {
  const float* in = (const float*)d_in[0];
  const float* cb = (const float*)d_in[1];
  const int* last_used = (const int*)d_in[2];

  float* out = (float*)d_out;
  float* out_idx = out;                       // 65536
  float* embed_out = out + NROWS;             // 16777216
  float* out_loss = embed_out + EMBED_ELEMS;  // 1
  float* out_lu = out_loss + 1;               // 1024

  _Float16* cb16 = (_Float16*)d_ws;                            // 512 KB (permuted)
  double* partials = (double*)(cb16 + NUM_EMBED * EMBED_DIM);  // 4096 double
  int* flagged = (int*)(partials + 4096);                      // 65536 int
  int* flagcount = flagged + NROWS;                            // 16 int
  int* idxi = flagcount + 16;                                  // 65536 int
  int* used = idxi + NROWS;                                    // 1024 int
  float* cnorm = (float*)(used + NUM_EMBED);                   // 1024 float

  hipLaunchKernelGGL(k_init, dim3(193), dim3(256), 0, stream, cb, used, flagcount, cnorm, cb16);
  hipLaunchKernelGGL(k_score, dim3(256), dim3(256), 0, stream, in, cb16, cnorm, out_idx,
                     idxi, flagged, flagcount, used);
  hipLaunchKernelGGL(k_cleanup, dim3(2048), dim3(256), 0, stream, in, cb, cnorm, flagged,
                     flagcount, out_idx, idxi, used);
  hipLaunchKernelGGL(k_gather, dim3(4096), dim3(256), 0, stream, in, cb, idxi, embed_out,
                     partials);
  hipLaunchKernelGGL(k_tail, dim3(1), dim3(256), 0, stream, partials, used, last_used,
                     out_loss, out_lu);
}

// Round 10
// 217.901 us; speedup vs baseline: 1.0255x; 1.0255x over previous
//
#include <hip/hip_runtime.h>

#define NUM_EMBED 1024
#define EMBED_DIM 256
#define SPATIAL 4096          // 64*64
#define NROWS 65536           // 16*4096
#define EMBED_ELEMS 16777216  // 16*256*4096
#define HMARGIN 0.05f         // margin on h = d2/2 scores (== 0.1 on d2)

typedef _Float16 half8 __attribute__((ext_vector_type(8)));
typedef float f32x4 __attribute__((ext_vector_type(4)));

__device__ __forceinline__ unsigned fkey(float f) {
  unsigned u = __float_as_uint(f);
  return (u & 0x80000000u) ? ~u : (u | 0x80000000u);
}

__device__ __forceinline__ void gll16(const _Float16* g, void* l) {
  __builtin_amdgcn_global_load_lds((const __attribute__((address_space(1))) void*)g,
                                   (__attribute__((address_space(3))) void*)l, 16, 0, 0);
}

#define UPD(V1, V2, I1, S, I)                            \
  { float _s = (S);                                      \
    if (_s < (V1)) { (V2) = (V1); (V1) = _s; (I1) = (I); } \
    else if (_s < (V2)) { (V2) = _s; } }

#define MERGE(V1A, V2A, I1A, V1B, V2B, I1B)                       \
  { if ((V1B) < (V1A)) { (V2A) = fminf((V1A), (V2B)); (V1A) = (V1B); (I1A) = (I1B); } \
    else { (V2A) = fminf((V2A), (V1B)); } }

// ---------------- init: used, flagcount, cnorm, cb16 (PERMUTED for k_score staging) ----------------
// cb16p half-index D = 8*gid, gid = c*1024 + i*256 + t  <-  source half-index
// S = c*8192 + (t&31)*256 + (t>>5)*8 + i*64.
__global__ __launch_bounds__(256) void k_init(const float* __restrict__ cb,
                                              int* __restrict__ used,
                                              int* __restrict__ flagcount,
                                              float* __restrict__ cnorm,
                                              _Float16* __restrict__ cb16) {
  int bid = blockIdx.x, tid = threadIdx.x;
  if (bid == 0) {
    used[tid] = 0; used[tid + 256] = 0; used[tid + 512] = 0; used[tid + 768] = 0;
    if (tid == 0) *flagcount = 0;
  } else if (bid <= 64) {
    int c = (bid - 1) * 16 + (tid >> 4);
    int l = tid & 15;
    const float4* p = (const float4*)(cb + c * EMBED_DIM + l * 16);
    float s = 0.f;
#pragma unroll
    for (int j = 0; j < 4; ++j) {
      float4 v = p[j];
      s += v.x * v.x + v.y * v.y + v.z * v.z + v.w * v.w;
    }
#pragma unroll
    for (int off = 1; off < 16; off <<= 1) s += __shfl_xor(s, off, 16);
    if (l == 0) cnorm[c] = s;
  } else {
    int gid = (bid - 65) * 256 + tid;  // 0..32767
    int c = gid >> 10;
    int rem = gid & 1023;
    int i = rem >> 8;
    int t = rem & 255;
    int S = c * 8192 + (t & 31) * 256 + (t >> 5) * 8 + i * 64;
    const float4* src = (const float4*)(cb + S);
    float4 a = src[0], b = src[1];
    half8 h;
    h[0] = (_Float16)a.x; h[1] = (_Float16)a.y; h[2] = (_Float16)a.z; h[3] = (_Float16)a.w;
    h[4] = (_Float16)b.x; h[5] = (_Float16)b.y; h[6] = (_Float16)b.z; h[7] = (_Float16)b.w;
    *(half8*)(cb16 + gid * 8) = h;
  }
}

// ---------------- fp16 MFMA screening, FAT WAVES (64 rows/wave), spill-free ----------------
// block: 256 rows = 4 waves x 64 rows; grid 256 (1 block/CU). Per chunk/wave:
// 64 MFMA vs 16 ds_read_b128 (4:1). X frags xf[8][4] in 64 VGPRs via two
// STATICALLY-UNROLLED 32-row transpose passes (rule #20: no runtime index).
// Codebook: 3-deep 16KB ring, counted vmcnt(4), stage(c+2) per chunk.
__global__ __launch_bounds__(256, 1) void k_score(const float* __restrict__ in,
                                                  const _Float16* __restrict__ cb16,
                                                  const float* __restrict__ cnorm,
                                                  float* __restrict__ out_idx,
                                                  int* __restrict__ idxi,
                                                  int* __restrict__ flagged,
                                                  int* __restrict__ flagcount,
                                                  int* __restrict__ used) {
  __shared__ _Float16 As[3][8192];   // 48 KB ring
  __shared__ _Float16 Sc[4][8192];   // 64 KB transpose scratch (16 KB/wave)
  __shared__ float cn_lds[1024];     // 4 KB, pre-scaled x0.5
  int tid = threadIdx.x;
  int lane = tid & 63;
  int wave = tid >> 6;
  int ln = lane & 15;
  int lg = lane >> 4;
  int r0 = blockIdx.x << 8;  // 256 rows/block
  const float* Ain = in + ((r0 >> 12) * (EMBED_DIM * SPATIAL)) + (r0 & 4095);

  // issue stage(chunk 0) NOW — latency hides under the transpose
  const _Float16* pc = cb16 + tid * 8;  // permuted: contiguous per wave instr
  char* AsB = (char*)As[0];
  int dsto = tid * 16;
#pragma unroll
  for (int i = 0; i < 4; ++i) gll16(pc + i * 2048, AsB + i * 4096 + dsto);

  // ---- X transpose: 2 STATIC passes x 32 rows through this wave's 16KB scratch ----
  half8 xf[8][4];
  {
    char* scratch = (char*)Sc[wave];
    int row = lane & 31;
    int h = lane >> 5;  // kc half: kc = h*16 + jj
    // ---- pass 0: rows 0..31 -> xf[ks][0..1] ----
    {
      const float* p0 = Ain + wave * 64 + row;
#pragma unroll
      for (int jj = 0; jj < 16; ++jj) {
        int kc = h * 16 + jj;
        half8 hv;
#pragma unroll
        for (int q = 0; q < 8; ++q) hv[q] = (_Float16)p0[(kc * 8 + q) * SPATIAL];
        *(half8*)(scratch + kc * 512 + row * 16) = hv;
      }
      asm volatile("s_waitcnt lgkmcnt(0)" ::: "memory");
      __builtin_amdgcn_sched_barrier(0);
#pragma unroll
      for (int ks = 0; ks < 8; ++ks) {
        xf[ks][0] = *(const half8*)(scratch + (ks * 4 + lg) * 512 + ln * 16);
        xf[ks][1] = *(const half8*)(scratch + (ks * 4 + lg) * 512 + (16 + ln) * 16);
      }
      asm volatile("s_waitcnt lgkmcnt(0)" ::: "memory");
      __builtin_amdgcn_sched_barrier(0);
    }
    // ---- pass 1: rows 32..63 -> xf[ks][2..3] ----
    {
      const float* p0 = Ain + wave * 64 + 32 + row;
#pragma unroll
      for (int jj = 0; jj < 16; ++jj) {
        int kc = h * 16 + jj;
        half8 hv;
#pragma unroll
        for (int q = 0; q < 8; ++q) hv[q] = (_Float16)p0[(kc * 8 + q) * SPATIAL];
        *(half8*)(scratch + kc * 512 + row * 16) = hv;
      }
      asm volatile("s_waitcnt lgkmcnt(0)" ::: "memory");
      __builtin_amdgcn_sched_barrier(0);
#pragma unroll
      for (int ks = 0; ks < 8; ++ks) {
        xf[ks][2] = *(const half8*)(scratch + (ks * 4 + lg) * 512 + ln * 16);
        xf[ks][3] = *(const half8*)(scratch + (ks * 4 + lg) * 512 + (16 + ln) * 16);
      }
      asm volatile("s_waitcnt lgkmcnt(0)" ::: "memory");
      __builtin_amdgcn_sched_barrier(0);
    }
  }

  // cnorm*0.5 -> LDS
#pragma unroll
  for (int i = 0; i < 4; ++i) cn_lds[tid + 256 * i] = 0.5f * cnorm[tid + 256 * i];
  __syncthreads();  // cn + chunk-0 visible ordering handled by vmcnt below

  // prologue: stage chunk 1 -> ring buffer 1
#pragma unroll
  for (int i = 0; i < 4; ++i) gll16(pc + 8192 + i * 2048, AsB + 16384 + i * 4096 + dsto);

  float sv1[4] = {3e38f, 3e38f, 3e38f, 3e38f};
  float sv2[4] = {3e38f, 3e38f, 3e38f, 3e38f};
  int si1[4] = {0, 0, 0, 0};

  const _Float16* pnext = pc + 2 * 8192;  // gll source for chunk c+2 (halves)
  int cur = 0;                            // ring BYTE offset of chunk c
  int nxt2 = 32768;                       // ring BYTE offset of chunk c+2
  int cbase = 0;

#pragma unroll 1
  for (int c = 0; c < 32; ++c) {
    if (c < 31) { asm volatile("s_waitcnt vmcnt(4)" ::: "memory"); }
    else        { asm volatile("s_waitcnt vmcnt(0)" ::: "memory"); }
    __builtin_amdgcn_s_barrier();
    asm volatile("" ::: "memory");
    if (c < 30) {
      char* dst = AsB + nxt2;
#pragma unroll
      for (int i = 0; i < 4; ++i) gll16(pnext + i * 2048, dst + i * 4096 + dsto);
      pnext += 8192;
    }
    const char* Ac = AsB + cur;
    f32x4 acc[2][4] = {};
    __builtin_amdgcn_s_setprio(1);
#pragma unroll
    for (int ks = 0; ks < 8; ++ks) {
      half8 af0 = *(const half8*)(Ac + ks * 2048 + lg * 512 + ln * 16);
      half8 af1 = *(const half8*)(Ac + ks * 2048 + lg * 512 + 256 + ln * 16);
#pragma unroll
      for (int nf = 0; nf < 4; ++nf) {
        acc[0][nf] = __builtin_amdgcn_mfma_f32_16x16x32_f16(af0, xf[ks][nf], acc[0][nf], 0, 0, 0);
        acc[1][nf] = __builtin_amdgcn_mfma_f32_16x16x32_f16(af1, xf[ks][nf], acc[1][nf], 0, 0, 0);
      }
    }
    __builtin_amdgcn_s_setprio(0);
    // fold: h = 0.5*|c|^2 - x.c ; codes cbase + {0,16} + lg*4 + r
    float cna[4], cnb[4];
    *(float4*)cna = *(const float4*)(cn_lds + cbase + lg * 4);
    *(float4*)cnb = *(const float4*)(cn_lds + cbase + 16 + lg * 4);
    int ib0 = cbase + lg * 4;
#pragma unroll
    for (int nf = 0; nf < 4; ++nf) {
      float v1a = cna[0] - acc[0][nf][0], v2a = 3e38f;
      int i1a = ib0;
      float v1b = cnb[0] - acc[1][nf][0], v2b = 3e38f;
      int i1b = ib0 + 16;
#pragma unroll
      for (int r = 1; r < 4; ++r) {
        UPD(v1a, v2a, i1a, cna[r] - acc[0][nf][r], ib0 + r);
        UPD(v1b, v2b, i1b, cnb[r] - acc[1][nf][r], ib0 + 16 + r);
      }
      MERGE(v1a, v2a, i1a, v1b, v2b, i1b);
      MERGE(sv1[nf], sv2[nf], si1[nf], v1a, v2a, i1a);
    }
    cbase += 32;
    cur += 16384; if (cur == 49152) cur = 0;
    nxt2 += 16384; if (nxt2 == 49152) nxt2 = 0;
  }

  // ---- merge the 4 lane-groups (same rows, disjoint codes); waves independent ----
#pragma unroll
  for (int nf = 0; nf < 4; ++nf) {
#pragma unroll
    for (int off = 16; off < 64; off <<= 1) {
      float ov1 = __shfl_xor(sv1[nf], off);
      float ov2 = __shfl_xor(sv2[nf], off);
      int oi = __shfl_xor(si1[nf], off);
      if (ov1 < sv1[nf]) { sv2[nf] = fminf(sv1[nf], ov2); sv1[nf] = ov1; si1[nf] = oi; }
      else { sv2[nf] = fminf(sv2[nf], ov1); }
    }
  }
  if (lg == 0) {
#pragma unroll
    for (int nf = 0; nf < 4; ++nf) {
      int grow = r0 + wave * 64 + nf * 16 + ln;
      out_idx[grow] = (float)si1[nf];
      idxi[grow] = si1[nf];
      if (sv2[nf] - sv1[nf] < HMARGIN) {
        int p = atomicAdd(flagcount, 1);
        flagged[p] = grow;
      } else {
        used[si1[nf]] = 1;  // final winner for unflagged rows (ties always flagged)
      }
    }
  }
}

// ---------------- exact fp32 re-rank: 1 flagged row per block, wave-per-code-slice ----------------
__global__ __launch_bounds__(256) void k_cleanup(const float* __restrict__ in,
                                                 const float* __restrict__ cb,
                                                 const float* __restrict__ cnorm,
                                                 const int* __restrict__ flagged,
                                                 const int* __restrict__ flagcount,
                                                 float* __restrict__ out_idx,
                                                 int* __restrict__ idxi,
                                                 int* __restrict__ used) {
  __shared__ unsigned long long red[4];
  int tid = threadIdx.x;
  int lane = tid & 63;
  int wave = tid >> 6;
  int nf = *flagcount;
  const float4* cb4 = (const float4*)cb;
  for (int fi = blockIdx.x; fi < nf; fi += 2048) {
    int row = flagged[fi];
    int b = row >> 12, s = row & 4095;
    const float* xp = in + b * (EMBED_DIM * SPATIAL) + s;
    float xk[4];
#pragma unroll
    for (int j = 0; j < 4; ++j) xk[j] = xp[(lane * 4 + j) * SPATIAL];
    unsigned long long best = ~0ull;
    int c0 = wave * 256;
#pragma unroll 4
    for (int cc = 0; cc < 256; ++cc) {
      int code = c0 + cc;
      float4 cv = cb4[code * 64 + lane];  // coalesced: 64 lanes x 16B
      float p = cv.x * xk[0] + cv.y * xk[1] + cv.z * xk[2] + cv.w * xk[3];
#pragma unroll
      for (int off = 1; off < 64; off <<= 1) p += __shfl_xor(p, off);
      float sc = cnorm[code] - 2.0f * p;
      unsigned long long k = ((unsigned long long)fkey(sc) << 32) | (unsigned)code;
      best = k < best ? k : best;
    }
    if (lane == 0) red[wave] = best;
    __syncthreads();
    if (tid == 0) {
      unsigned long long bb = red[0];
#pragma unroll
      for (int w = 1; w < 4; ++w) { unsigned long long o = red[w]; bb = o < bb ? o : bb; }
      int idx = (int)(bb & 0xffffffffull);
      out_idx[row] = (float)idx;
      idxi[row] = idx;
      used[idx] = 1;
    }
    __syncthreads();
  }
}

// ---------------- gather embed + MSE partial sums ----------------
__global__ __launch_bounds__(256) void k_gather(const float* __restrict__ in,
                                                const float* __restrict__ cb,
                                                const int* __restrict__ idxi,
                                                float* __restrict__ embed_out,
                                                double* __restrict__ partials) {
  int tid = threadIdx.x;
  float lsum = 0.f;
#pragma unroll
  for (int it = 0; it < 4; ++it) {
    int gid = (it * 4096 + blockIdx.x) * 256 + tid;
    int b = gid >> 18;
    int r = gid & 262143;
    int d = r >> 10;
    int s4 = r & 1023;
    int4 id4 = *(const int4*)(idxi + (b << 12) + (s4 << 2));
    int off = ((b * EMBED_DIM + d) << 12) + (s4 << 2);
    float4 x = *(const float4*)(in + off);
    float4 e;
    e.x = cb[id4.x * EMBED_DIM + d];
    e.y = cb[id4.y * EMBED_DIM + d];
    e.z = cb[id4.z * EMBED_DIM + d];
    e.w = cb[id4.w * EMBED_DIM + d];
    *(float4*)(embed_out + off) = e;
    float dx = e.x - x.x, dy = e.y - x.y, dz = e.z - x.z, dw = e.w - x.w;
    lsum += dx * dx + dy * dy + dz * dz + dw * dw;
  }
#pragma unroll
  for (int off = 1; off < 64; off <<= 1) lsum += __shfl_xor(lsum, off, 64);
  __shared__ float wsum[4];
  if ((tid & 63) == 0) wsum[tid >> 6] = lsum;
  __syncthreads();
  if (tid == 0)
    partials[blockIdx.x] = (double)(wsum[0] + wsum[1] + wsum[2] + wsum[3]);
}

// ---------------- tail: loss scalar + new_last_used ----------------
__global__ __launch_bounds__(256) void k_tail(const double* __restrict__ partials,
                                              const int* __restrict__ used,
                                              const int* __restrict__ last_used,
                                              float* __restrict__ out_loss,
                                              float* __restrict__ out_lu) {
  int tid = threadIdx.x;
  double s = 0.0;
  for (int i = tid; i < 4096; i += 256) s += partials[i];
#pragma unroll
  for (int off = 1; off < 64; off <<= 1) s += __shfl_xor(s, off, 64);
  __shared__ double sd[4];
  if ((tid & 63) == 0) sd[tid >> 6] = s;
  __syncthreads();
  if (tid == 0) {
    double total = sd[0] + sd[1] + sd[2] + sd[3];
    out_loss[0] = (float)(1.25 * total / (double)EMBED_ELEMS);
  }
  for (int i = tid; i < NUM_EMBED; i += 256)
    out_lu[i] = used[i] ? 0.0f : (float)(last_used[i] + 1);
}

extern "C" void kernel_launch(void* const* d_in, const int* in_sizes, int n_in,
                              void* d_out, int out_size, void* d_ws, size_t ws_size,
                              hipStream_t stream) {
  const float* in = (const float*)d_in[0];
  const float* cb = (const float*)d_in[1];
  const int* last_used = (const int*)d_in[2];

  float* out = (float*)d_out;
  float* out_idx = out;                       // 65536
  float* embed_out = out + NROWS;             // 16777216
  float* out_loss = embed_out + EMBED_ELEMS;  // 1
  float* out_lu = out_loss + 1;               // 1024

  _Float16* cb16 = (_Float16*)d_ws;                            // 512 KB (permuted)
  double* partials = (double*)(cb16 + NUM_EMBED * EMBED_DIM);  // 4096 double
  int* flagged = (int*)(partials + 4096);                      // 65536 int
  int* flagcount = flagged + NROWS;                            // 16 int
  int* idxi = flagcount + 16;                                  // 65536 int
  int* used = idxi + NROWS;                                    // 1024 int
  float* cnorm = (float*)(used + NUM_EMBED);                   // 1024 float

  hipLaunchKernelGGL(k_init, dim3(193), dim3(256), 0, stream, cb, used, flagcount, cnorm, cb16);
  hipLaunchKernelGGL(k_score, dim3(256), dim3(256), 0, stream, in, cb16, cnorm, out_idx,
                     idxi, flagged, flagcount, used);
  hipLaunchKernelGGL(k_cleanup, dim3(2048), dim3(256), 0, stream, in, cb, cnorm, flagged,
                     flagcount, out_idx, idxi, used);
  hipLaunchKernelGGL(k_gather, dim3(4096), dim3(256), 0, stream, in, cb, idxi, embed_out,
                     partials);
  hipLaunchKernelGGL(k_tail, dim3(1), dim3(256), 0, stream, partials, used, last_used,
                     out_loss, out_lu);
}

// Round 11
// 161.604 us; speedup vs baseline: 1.3827x; 1.3484x over previous
//
#include <hip/hip_runtime.h>

#define NUM_EMBED 1024
#define EMBED_DIM 256
#define SPATIAL 4096          // 64*64
#define NROWS 65536           // 16*4096
#define EMBED_ELEMS 16777216  // 16*256*4096
#define HMARGIN 0.05f         // margin on h = d2/2 scores (== 0.1 on d2)

typedef _Float16 half8 __attribute__((ext_vector_type(8)));
typedef float f32x4 __attribute__((ext_vector_type(4)));

__device__ __forceinline__ unsigned fkey(float f) {
  unsigned u = __float_as_uint(f);
  return (u & 0x80000000u) ? ~u : (u | 0x80000000u);
}

__device__ __forceinline__ void gll16(const _Float16* g, void* l) {
  __builtin_amdgcn_global_load_lds((const __attribute__((address_space(1))) void*)g,
                                   (__attribute__((address_space(3))) void*)l, 16, 0, 0);
}

#define UPD(V1, V2, I1, S, I)                            \
  { float _s = (S);                                      \
    if (_s < (V1)) { (V2) = (V1); (V1) = _s; (I1) = (I); } \
    else if (_s < (V2)) { (V2) = _s; } }

#define MERGE(V1A, V2A, I1A, V1B, V2B, I1B)                       \
  { if ((V1B) < (V1A)) { (V2A) = fminf((V1A), (V2B)); (V1A) = (V1B); (I1A) = (I1B); } \
    else { (V2A) = fminf((V2A), (V1B)); } }

// ---------------- init: used, flagcount, cnorm, cb16 (PERMUTED for k_score staging) ----------------
// cb16p half-index D = 8*gid, gid = c*1024 + i*256 + t  <-  source half-index
// S = c*8192 + (t&31)*256 + (t>>5)*8 + i*64.
__global__ __launch_bounds__(256) void k_init(const float* __restrict__ cb,
                                              int* __restrict__ used,
                                              int* __restrict__ flagcount,
                                              float* __restrict__ cnorm,
                                              _Float16* __restrict__ cb16) {
  int bid = blockIdx.x, tid = threadIdx.x;
  if (bid == 0) {
    used[tid] = 0; used[tid + 256] = 0; used[tid + 512] = 0; used[tid + 768] = 0;
    if (tid == 0) *flagcount = 0;
  } else if (bid <= 64) {
    int c = (bid - 1) * 16 + (tid >> 4);
    int l = tid & 15;
    const float4* p = (const float4*)(cb + c * EMBED_DIM + l * 16);
    float s = 0.f;
#pragma unroll
    for (int j = 0; j < 4; ++j) {
      float4 v = p[j];
      s += v.x * v.x + v.y * v.y + v.z * v.z + v.w * v.w;
    }
#pragma unroll
    for (int off = 1; off < 16; off <<= 1) s += __shfl_xor(s, off, 16);
    if (l == 0) cnorm[c] = s;
  } else {
    int gid = (bid - 65) * 256 + tid;  // 0..32767
    int c = gid >> 10;
    int rem = gid & 1023;
    int i = rem >> 8;
    int t = rem & 255;
    int S = c * 8192 + (t & 31) * 256 + (t >> 5) * 8 + i * 64;
    const float4* src = (const float4*)(cb + S);
    float4 a = src[0], b = src[1];
    half8 h;
    h[0] = (_Float16)a.x; h[1] = (_Float16)a.y; h[2] = (_Float16)a.z; h[3] = (_Float16)a.w;
    h[4] = (_Float16)b.x; h[5] = (_Float16)b.y; h[6] = (_Float16)b.z; h[7] = (_Float16)b.w;
    *(half8*)(cb16 + gid * 8) = h;
  }
}

// ---------------- fp16 MFMA screening (R8 structure, permuted staging sources) ----------------
// block: 128 rows = 4 waves x 32 rows; grid 512 (2 blocks/CU). X frags xf[8][2]
// in registers (one-time LDS transpose in ring scratch). Codebook chunks
// (32 codes x K=256, 16 KB) staged by gll16 into a 3-deep ring, counted
// vmcnt(4), one raw s_barrier per chunk; rolled main loop.
__global__ __launch_bounds__(256, 2) void k_score(const float* __restrict__ in,
                                                  const _Float16* __restrict__ cb16,
                                                  const float* __restrict__ cnorm,
                                                  float* __restrict__ out_idx,
                                                  int* __restrict__ idxi,
                                                  int* __restrict__ flagged,
                                                  int* __restrict__ flagcount,
                                                  int* __restrict__ used) {
  __shared__ _Float16 As[3][8192];  // 48 KB ring (also transpose scratch)
  __shared__ float cn_lds[1024];    // 4 KB, pre-scaled x0.5
  int tid = threadIdx.x;
  int lane = tid & 63;
  int wave = tid >> 6;
  int ln = lane & 15;
  int lg = lane >> 4;
  int r0 = blockIdx.x << 7;  // 128 rows/block
  const float* Ain = in + ((r0 >> 12) * (EMBED_DIM * SPATIAL)) + (r0 & 4095);

  // ---- one-time X transpose: wave w stages its 32 rows, reads back fragments ----
  half8 xf[8][2];
  {
    int row = lane & 31;
    int khalf = lane >> 5;  // 0/1
    const float* p0 = Ain + wave * 32 + row;
    if (wave < 3) {
      char* base = (char*)As[wave];
#pragma unroll
      for (int j = 0; j < 16; ++j) {
        int kc = khalf * 16 + j;
        half8 h;
#pragma unroll
        for (int q = 0; q < 8; ++q) h[q] = (_Float16)p0[(kc * 8 + q) * SPATIAL];
        *(half8*)(base + kc * 512 + row * 16) = h;
      }
    }
    // cnorm*0.5 -> LDS (cooperative)
#pragma unroll
    for (int i = 0; i < 4; ++i) cn_lds[tid + 256 * i] = 0.5f * cnorm[tid + 256 * i];
    __syncthreads();
    if (wave < 3) {
      const char* base = (const char*)As[wave];
#pragma unroll
      for (int ks = 0; ks < 8; ++ks)
#pragma unroll
        for (int nf = 0; nf < 2; ++nf)
          xf[ks][nf] = *(const half8*)(base + (ks * 4 + lg) * 512 + (nf * 16 + ln) * 16);
    }
    __syncthreads();  // waves 0..2 done reading before wave 3 reuses As[0]
    if (wave == 3) {
      char* base = (char*)As[0];
#pragma unroll
      for (int j = 0; j < 16; ++j) {
        int kc = khalf * 16 + j;
        half8 h;
#pragma unroll
        for (int q = 0; q < 8; ++q) h[q] = (_Float16)p0[(kc * 8 + q) * SPATIAL];
        *(half8*)(base + kc * 512 + row * 16) = h;
      }
      const char* cbase2 = (const char*)As[0];
#pragma unroll
      for (int ks = 0; ks < 8; ++ks)
#pragma unroll
        for (int nf = 0; nf < 2; ++nf)
          xf[ks][nf] = *(const half8*)(cbase2 + (ks * 4 + lg) * 512 + (nf * 16 + ln) * 16);
    }
    __syncthreads();  // As free for codebook ring
  }

  // permuted cb16: per-thread gll sources are contiguous (1 KB per wave instr)
  const _Float16* pc = cb16 + tid * 8;
  char* AsB = (char*)As[0];
  int dsto = tid * 16;

  // prologue: chunks 0,1 -> ring buffers 0,1 (16384 BYTES apart)
#pragma unroll
  for (int i = 0; i < 4; ++i) gll16(pc + i * 2048, AsB + i * 4096 + dsto);
#pragma unroll
  for (int i = 0; i < 4; ++i) gll16(pc + 8192 + i * 2048, AsB + 16384 + i * 4096 + dsto);

  float sv1[2] = {3e38f, 3e38f}, sv2[2] = {3e38f, 3e38f};
  int si1[2] = {0, 0};

  const _Float16* pnext = pc + 2 * 8192;  // gll source for chunk c+2 (halves)
  int cur = 0;                            // ring BYTE offset of chunk c
  int nxt2 = 32768;                       // ring BYTE offset of chunk c+2
  int cbase = 0;                          // first code id of chunk c
  int afo0 = lg * 512 + ln * 16;          // A-frag offset (+ks*2048, +mf*256)

#pragma unroll 1
  for (int c = 0; c < 32; ++c) {
    if (c < 31) { asm volatile("s_waitcnt vmcnt(4)" ::: "memory"); }
    else        { asm volatile("s_waitcnt vmcnt(0)" ::: "memory"); }
    __builtin_amdgcn_s_barrier();
    asm volatile("" ::: "memory");
    if (c < 30) {
      char* dst = AsB + nxt2;
#pragma unroll
      for (int i = 0; i < 4; ++i) gll16(pnext + i * 2048, dst + i * 4096 + dsto);
      pnext += 8192;
    }
    const char* Ac = AsB + cur;
    f32x4 acc[2][2] = {};
    __builtin_amdgcn_s_setprio(1);
#pragma unroll
    for (int ks = 0; ks < 8; ++ks) {
      half8 af0 = *(const half8*)(Ac + ks * 2048 + afo0);
      half8 af1 = *(const half8*)(Ac + ks * 2048 + afo0 + 256);
      acc[0][0] = __builtin_amdgcn_mfma_f32_16x16x32_f16(af0, xf[ks][0], acc[0][0], 0, 0, 0);
      acc[0][1] = __builtin_amdgcn_mfma_f32_16x16x32_f16(af0, xf[ks][1], acc[0][1], 0, 0, 0);
      acc[1][0] = __builtin_amdgcn_mfma_f32_16x16x32_f16(af1, xf[ks][0], acc[1][0], 0, 0, 0);
      acc[1][1] = __builtin_amdgcn_mfma_f32_16x16x32_f16(af1, xf[ks][1], acc[1][1], 0, 0, 0);
    }
    __builtin_amdgcn_s_setprio(0);
    // fold chunk: h = 0.5*|c|^2 - x.c ; two 4-deep chains per nf, then merges
    float cna[4], cnb[4];
    *(float4*)cna = *(const float4*)(cn_lds + cbase + lg * 4);
    *(float4*)cnb = *(const float4*)(cn_lds + cbase + 16 + lg * 4);
    int ib0 = cbase + lg * 4;
#pragma unroll
    for (int nf = 0; nf < 2; ++nf) {
      float v1a = cna[0] - acc[0][nf][0], v2a = 3e38f;
      int i1a = ib0;
      float v1b = cnb[0] - acc[1][nf][0], v2b = 3e38f;
      int i1b = ib0 + 16;
#pragma unroll
      for (int r = 1; r < 4; ++r) {
        UPD(v1a, v2a, i1a, cna[r] - acc[0][nf][r], ib0 + r);
        UPD(v1b, v2b, i1b, cnb[r] - acc[1][nf][r], ib0 + 16 + r);
      }
      MERGE(v1a, v2a, i1a, v1b, v2b, i1b);
      MERGE(sv1[nf], sv2[nf], si1[nf], v1a, v2a, i1a);
    }
    cbase += 32;
    cur += 16384; if (cur == 49152) cur = 0;
    nxt2 += 16384; if (nxt2 == 49152) nxt2 = 0;
  }

  // ---- merge the 4 lane-groups (same rows, disjoint codes); waves independent ----
#pragma unroll
  for (int nf = 0; nf < 2; ++nf) {
#pragma unroll
    for (int off = 16; off < 64; off <<= 1) {
      float ov1 = __shfl_xor(sv1[nf], off);
      float ov2 = __shfl_xor(sv2[nf], off);
      int oi = __shfl_xor(si1[nf], off);
      if (ov1 < sv1[nf]) { sv2[nf] = fminf(sv1[nf], ov2); sv1[nf] = ov1; si1[nf] = oi; }
      else { sv2[nf] = fminf(sv2[nf], ov1); }
    }
  }
  if (lg == 0) {
#pragma unroll
    for (int nf = 0; nf < 2; ++nf) {
      int grow = r0 + wave * 32 + nf * 16 + ln;
      out_idx[grow] = (float)si1[nf];
      idxi[grow] = si1[nf];
      if (sv2[nf] - sv1[nf] < HMARGIN) {
        int p = atomicAdd(flagcount, 1);
        flagged[p] = grow;
      } else {
        used[si1[nf]] = 1;  // final winner for unflagged rows (ties always flagged)
      }
    }
  }
}

// ---------------- exact fp32 re-rank: 1 flagged row per block, wave-per-code-slice ----------------
__global__ __launch_bounds__(256) void k_cleanup(const float* __restrict__ in,
                                                 const float* __restrict__ cb,
                                                 const float* __restrict__ cnorm,
                                                 const int* __restrict__ flagged,
                                                 const int* __restrict__ flagcount,
                                                 float* __restrict__ out_idx,
                                                 int* __restrict__ idxi,
                                                 int* __restrict__ used) {
  __shared__ unsigned long long red[4];
  int tid = threadIdx.x;
  int lane = tid & 63;
  int wave = tid >> 6;
  int nf = *flagcount;
  const float4* cb4 = (const float4*)cb;
  for (int fi = blockIdx.x; fi < nf; fi += 2048) {
    int row = flagged[fi];
    int b = row >> 12, s = row & 4095;
    const float* xp = in + b * (EMBED_DIM * SPATIAL) + s;
    float xk[4];
#pragma unroll
    for (int j = 0; j < 4; ++j) xk[j] = xp[(lane * 4 + j) * SPATIAL];
    unsigned long long best = ~0ull;
    int c0 = wave * 256;
#pragma unroll 4
    for (int cc = 0; cc < 256; ++cc) {
      int code = c0 + cc;
      float4 cv = cb4[code * 64 + lane];  // coalesced: 64 lanes x 16B
      float p = cv.x * xk[0] + cv.y * xk[1] + cv.z * xk[2] + cv.w * xk[3];
#pragma unroll
      for (int off = 1; off < 64; off <<= 1) p += __shfl_xor(p, off);
      float sc = cnorm[code] - 2.0f * p;
      unsigned long long k = ((unsigned long long)fkey(sc) << 32) | (unsigned)code;
      best = k < best ? k : best;
    }
    if (lane == 0) red[wave] = best;
    __syncthreads();
    if (tid == 0) {
      unsigned long long bb = red[0];
#pragma unroll
      for (int w = 1; w < 4; ++w) { unsigned long long o = red[w]; bb = o < bb ? o : bb; }
      int idx = (int)(bb & 0xffffffffull);
      out_idx[row] = (float)idx;
      idxi[row] = idx;
      used[idx] = 1;
    }
    __syncthreads();
  }
}

// ---------------- gather embed + MSE, transpose-tile (coalesced cb reads) ----------------
// block: 64 consecutive spatial positions x all 256 d. Phase 1: each wave reads
// 16 full codebook rows COALESCED (64 lanes x float4 = 1 KB row) into padded LDS
// E[64][257] (2-way conflicts only). Phase 2: wave w streams d in [64w,64w+64);
// in-read and embed-write fully coalesced; E read transposed (pad fixes banks).
__global__ __launch_bounds__(256) void k_gather(const float* __restrict__ in,
                                                const float* __restrict__ cb,
                                                const int* __restrict__ idxi,
                                                float* __restrict__ embed_out,
                                                double* __restrict__ partials) {
  __shared__ float E[64][257];  // ~66 KB
  __shared__ int idx_l[64];
  __shared__ float wsum[4];
  int tid = threadIdx.x;
  int lane = tid & 63;
  int wave = tid >> 6;
  int r0 = blockIdx.x << 6;  // 64 spatial positions (same batch: 4096 % 64 == 0)
  int b = r0 >> 12;
  int s0 = r0 & 4095;
  if (tid < 64) idx_l[tid] = idxi[r0 + tid];
  __syncthreads();
  const float4* cb4 = (const float4*)cb;
#pragma unroll
  for (int jj = 0; jj < 16; ++jj) {
    int j = wave * 16 + jj;
    float4 v = cb4[idx_l[j] * 64 + lane];
    E[j][lane * 4 + 0] = v.x;
    E[j][lane * 4 + 1] = v.y;
    E[j][lane * 4 + 2] = v.z;
    E[j][lane * 4 + 3] = v.w;
  }
  __syncthreads();
  float lsum = 0.f;
  int dbase = wave * 64;
  const float* inp = in + (b * EMBED_DIM + dbase) * SPATIAL + s0;
  float* outp = embed_out + (b * EMBED_DIM + dbase) * SPATIAL + s0;
#pragma unroll 8
  for (int dd = 0; dd < 64; ++dd) {
    float e = E[lane][dbase + dd];
    float x = inp[dd * SPATIAL + lane];
    outp[dd * SPATIAL + lane] = e;
    float df = e - x;
    lsum += df * df;
  }
#pragma unroll
  for (int off = 1; off < 64; off <<= 1) lsum += __shfl_xor(lsum, off, 64);
  if (lane == 0) wsum[wave] = lsum;
  __syncthreads();
  if (tid == 0)
    partials[blockIdx.x] = (double)(wsum[0] + wsum[1] + wsum[2] + wsum[3]);
}

// ---------------- tail: loss scalar + new_last_used ----------------
__global__ __launch_bounds__(256) void k_tail(const double* __restrict__ partials,
                                              const int* __restrict__ used,
                                              const int* __restrict__ last_used,
                                              float* __restrict__ out_loss,
                                              float* __restrict__ out_lu) {
  int tid = threadIdx.x;
  double s = 0.0;
  for (int i = tid; i < 1024; i += 256) s += partials[i];
#pragma unroll
  for (int off = 1; off < 64; off <<= 1) s += __shfl_xor(s, off, 64);
  __shared__ double sd[4];
  if ((tid & 63) == 0) sd[tid >> 6] = s;
  __syncthreads();
  if (tid == 0) {
    double total = sd[0] + sd[1] + sd[2] + sd[3];
    out_loss[0] = (float)(1.25 * total / (double)EMBED_ELEMS);
  }
  for (int i = tid; i < NUM_EMBED; i += 256)
    out_lu[i] = used[i] ? 0.0f : (float)(last_used[i] + 1);
}

extern "C" void kernel_launch(void* const* d_in, const int* in_sizes, int n_in,
                              void* d_out, int out_size, void* d_ws, size_t ws_size,
                              hipStream_t stream) {
  const float* in = (const float*)d_in[0];
  const float* cb = (const float*)d_in[1];
  const int* last_used = (const int*)d_in[2];

  float* out = (float*)d_out;
  float* out_idx = out;                       // 65536
  float* embed_out = out + NROWS;             // 16777216
  float* out_loss = embed_out + EMBED_ELEMS;  // 1
  float* out_lu = out_loss + 1;               // 1024

  _Float16* cb16 = (_Float16*)d_ws;                            // 512 KB (permuted)
  double* partials = (double*)(cb16 + NUM_EMBED * EMBED_DIM);  // 4096 double (1024 used)
  int* flagged = (int*)(partials + 4096);                      // 65536 int
  int* flagcount = flagged + NROWS;                            // 16 int
  int* idxi = flagcount + 16;                                  // 65536 int
  int* used = idxi + NROWS;                                    // 1024 int
  float* cnorm = (float*)(used + NUM_EMBED);                   // 1024 float

  hipLaunchKernelGGL(k_init, dim3(193), dim3(256), 0, stream, cb, used, flagcount, cnorm, cb16);
  hipLaunchKernelGGL(k_score, dim3(512), dim3(256), 0, stream, in, cb16, cnorm, out_idx,
                     idxi, flagged, flagcount, used);
  hipLaunchKernelGGL(k_cleanup, dim3(2048), dim3(256), 0, stream, in, cb, cnorm, flagged,
                     flagcount, out_idx, idxi, used);
  hipLaunchKernelGGL(k_gather, dim3(1024), dim3(256), 0, stream, in, cb, idxi, embed_out,
                     partials);
  hipLaunchKernelGGL(k_tail, dim3(1), dim3(256), 0, stream, partials, used, last_used,
                     out_loss, out_lu);
}

// Round 12
// 155.521 us; speedup vs baseline: 1.4368x; 1.0391x over previous
//
#include <hip/hip_runtime.h>

#define NUM_EMBED 1024
#define EMBED_DIM 256
#define SPATIAL 4096          // 64*64
#define NROWS 65536           // 16*4096
#define EMBED_ELEMS 16777216  // 16*256*4096
#define HMARGIN 0.05f         // margin on h = d2/2 scores (== 0.1 on d2)

typedef _Float16 half8 __attribute__((ext_vector_type(8)));
typedef float f32x4 __attribute__((ext_vector_type(4)));

__device__ __forceinline__ unsigned fkey(float f) {
  unsigned u = __float_as_uint(f);
  return (u & 0x80000000u) ? ~u : (u | 0x80000000u);
}

__device__ __forceinline__ void gll16(const _Float16* g, void* l) {
  __builtin_amdgcn_global_load_lds((const __attribute__((address_space(1))) void*)g,
                                   (__attribute__((address_space(3))) void*)l, 16, 0, 0);
}

#define UPD(V1, V2, I1, S, I)                            \
  { float _s = (S);                                      \
    if (_s < (V1)) { (V2) = (V1); (V1) = _s; (I1) = (I); } \
    else if (_s < (V2)) { (V2) = _s; } }

#define MERGE(V1A, V2A, I1A, V1B, V2B, I1B)                       \
  { if ((V1B) < (V1A)) { (V2A) = fminf((V1A), (V2B)); (V1A) = (V1B); (I1A) = (I1B); } \
    else { (V2A) = fminf((V2A), (V1B)); } }

// ---------------- init: used, flagcount, cnorm, cb16 (PERMUTED, 16-code chunks) ----------------
// cb16p[ch*4096 + ks*512 + lane*8 + q] = cb[(ch*16 + (lane&15))*256 + ks*32 + (lane>>4)*8 + q]
// so k_score's per-wave gll16 sources are lane-contiguous (1 KB per wave instruction).
__global__ __launch_bounds__(256) void k_init(const float* __restrict__ cb,
                                              int* __restrict__ used,
                                              int* __restrict__ flagcount,
                                              float* __restrict__ cnorm,
                                              _Float16* __restrict__ cb16) {
  int bid = blockIdx.x, tid = threadIdx.x;
  if (bid == 0) {
    used[tid] = 0; used[tid + 256] = 0; used[tid + 512] = 0; used[tid + 768] = 0;
    if (tid == 0) *flagcount = 0;
  } else if (bid <= 64) {
    int c = (bid - 1) * 16 + (tid >> 4);
    int l = tid & 15;
    const float4* p = (const float4*)(cb + c * EMBED_DIM + l * 16);
    float s = 0.f;
#pragma unroll
    for (int j = 0; j < 4; ++j) {
      float4 v = p[j];
      s += v.x * v.x + v.y * v.y + v.z * v.z + v.w * v.w;
    }
#pragma unroll
    for (int off = 1; off < 16; off <<= 1) s += __shfl_xor(s, off, 16);
    if (l == 0) cnorm[c] = s;
  } else {
    int gid = (bid - 65) * 256 + tid;  // 0..32767
    int ch = gid >> 9;                 // 64 chunks of 16 codes
    int rem = gid & 511;
    int ks = rem >> 6;
    int lg = (rem >> 4) & 3;
    int ln = rem & 15;
    int S = (ch * 16 + ln) * 256 + ks * 32 + lg * 8;
    const float4* src = (const float4*)(cb + S);
    float4 a = src[0], b = src[1];
    half8 h;
    h[0] = (_Float16)a.x; h[1] = (_Float16)a.y; h[2] = (_Float16)a.z; h[3] = (_Float16)a.w;
    h[4] = (_Float16)b.x; h[5] = (_Float16)b.y; h[6] = (_Float16)b.z; h[7] = (_Float16)b.w;
    *(half8*)(cb16 + gid * 8) = h;
  }
}

// ---------------- fp16 MFMA screening: CODE-PARTITIONED, BARRIER-FREE main loop ----------------
// block: 64 rows shared by 4 waves; wave w screens codes [256w, 256w+256) as 16
// chunks of 16 codes. X frags xf[8][4] replicated in registers per wave (one
// block-wide transpose). Each wave has a PRIVATE 2-deep 8KB LDS ring staged by
// per-wave gll16 with counted vmcnt(8) — no s_barrier in the loop; waves drift.
__global__ __launch_bounds__(256, 2) void k_score(const float* __restrict__ in,
                                                  const _Float16* __restrict__ cb16,
                                                  const float* __restrict__ cnorm,
                                                  float* __restrict__ out_idx,
                                                  int* __restrict__ idxi,
                                                  int* __restrict__ flagged,
                                                  int* __restrict__ flagcount,
                                                  int* __restrict__ used) {
  __shared__ _Float16 As[8][4096];  // 64 KB: wave w owns 16 KB (2 x 8 KB ring); also X scratch
  __shared__ float cn_lds[1024];    // 4 KB, pre-scaled x0.5
  int tid = threadIdx.x;
  int lane = tid & 63;
  int wave = tid >> 6;
  int ln = lane & 15;
  int lg = lane >> 4;
  int r0 = blockIdx.x << 6;  // 64 rows/block
  const float* Ain = in + ((r0 >> 12) * (EMBED_DIM * SPATIAL)) + (r0 & 4095);

  // ---- block-wide X transpose into first 32 KB: [kc 0..31][row 0..63] 16B ----
  {
    char* scratch = (char*)As[0];
    int row = tid & 63;
    int kq = tid >> 6;
    const float* p0 = Ain + row;
#pragma unroll
    for (int j = 0; j < 8; ++j) {
      int kc = kq * 8 + j;
      half8 hv;
#pragma unroll
      for (int q = 0; q < 8; ++q) hv[q] = (_Float16)p0[(kc * 8 + q) * SPATIAL];
      *(half8*)(scratch + kc * 1024 + row * 16) = hv;
    }
#pragma unroll
    for (int i = 0; i < 4; ++i) cn_lds[tid + 256 * i] = 0.5f * cnorm[tid + 256 * i];
  }
  __syncthreads();
  half8 xf[8][4];  // 128 VGPR: all 64 rows x K=256
  {
    const char* scratch = (const char*)As[0];
#pragma unroll
    for (int ks = 0; ks < 8; ++ks)
#pragma unroll
      for (int nf = 0; nf < 4; ++nf)
        xf[ks][nf] = *(const half8*)(scratch + (ks * 4 + lg) * 1024 + (nf * 16 + ln) * 16);
  }
  __syncthreads();  // scratch free for the rings; last barrier before epilogue

  // per-wave ring + permuted source base (wave w -> chunks 16w..16w+15)
  char* ring = (char*)As[0] + wave * 16384;
  const _Float16* src0 = cb16 + wave * 65536 + lane * 8;

  // prologue: stage chunk 0 -> ring buf 0 (8 gll16 = 8 KB per wave)
#pragma unroll
  for (int i = 0; i < 8; ++i) gll16(src0 + i * 512, ring + i * 1024 + lane * 16);

  float sv1[4] = {3e38f, 3e38f, 3e38f, 3e38f};
  float sv2[4] = {3e38f, 3e38f, 3e38f, 3e38f};
  int si1[4] = {0, 0, 0, 0};
  int afo = lg * 256 + ln * 16;

#pragma unroll 1
  for (int c = 0; c < 16; ++c) {
    if (c < 15) {  // issue stage(c+1) into the other buffer, then counted wait
      char* dst = ring + ((c + 1) & 1) * 8192;
      const _Float16* ps = src0 + (c + 1) * 4096;
#pragma unroll
      for (int i = 0; i < 8; ++i) gll16(ps + i * 512, dst + i * 1024 + lane * 16);
      asm volatile("s_waitcnt vmcnt(8)" ::: "memory");  // chunk c landed; c+1 in flight
    } else {
      asm volatile("s_waitcnt vmcnt(0)" ::: "memory");
    }
    __builtin_amdgcn_sched_barrier(0);  // rule #18: keep ds_reads below the wait
    const char* Ac = ring + (c & 1) * 8192;
    f32x4 acc[4] = {};
    __builtin_amdgcn_s_setprio(1);
#pragma unroll
    for (int ks = 0; ks < 8; ++ks) {
      half8 af = *(const half8*)(Ac + ks * 1024 + afo);
#pragma unroll
      for (int nf = 0; nf < 4; ++nf)
        acc[nf] = __builtin_amdgcn_mfma_f32_16x16x32_f16(af, xf[ks][nf], acc[nf], 0, 0, 0);
    }
    __builtin_amdgcn_s_setprio(0);
    // fold: h = 0.5*|c|^2 - x.c ; codes cb0 + lg*4 + r, rows nf*16+ln
    int cb0 = wave * 256 + c * 16;
    float cna[4];
    *(float4*)cna = *(const float4*)(cn_lds + cb0 + lg * 4);
    int ib0 = cb0 + lg * 4;
#pragma unroll
    for (int nf = 0; nf < 4; ++nf) {
      float v1a = cna[0] - acc[nf][0], v2a = 3e38f;
      int i1a = ib0;
#pragma unroll
      for (int r = 1; r < 4; ++r) UPD(v1a, v2a, i1a, cna[r] - acc[nf][r], ib0 + r);
      MERGE(sv1[nf], sv2[nf], si1[nf], v1a, v2a, i1a);
    }
  }

  // ---- merge the 4 lane-groups (same rows, disjoint codes within the wave) ----
#pragma unroll
  for (int nf = 0; nf < 4; ++nf) {
#pragma unroll
    for (int off = 16; off < 64; off <<= 1) {
      float ov1 = __shfl_xor(sv1[nf], off);
      float ov2 = __shfl_xor(sv2[nf], off);
      int oi = __shfl_xor(si1[nf], off);
      if (ov1 < sv1[nf]) { sv2[nf] = fminf(sv1[nf], ov2); sv1[nf] = ov1; si1[nf] = oi; }
      else { sv2[nf] = fminf(sv2[nf], ov1); }
    }
  }

  // ---- cross-wave merge: waves hold disjoint code quarters of the SAME rows ----
  __syncthreads();  // all waves done with rings
  float* mv1 = (float*)As[0];       // 256 f
  float* mv2 = mv1 + 256;
  int* mi1 = (int*)(mv2 + 256);
  if (lg == 0) {
#pragma unroll
    for (int nf = 0; nf < 4; ++nf) {
      int slot = wave * 64 + nf * 16 + ln;
      mv1[slot] = sv1[nf]; mv2[slot] = sv2[nf]; mi1[slot] = si1[nf];
    }
  }
  __syncthreads();
  if (tid < 64) {
    float v1 = mv1[tid], v2 = mv2[tid];
    int i1 = mi1[tid];
#pragma unroll
    for (int w = 1; w < 4; ++w)  // ascending code ranges: ties keep lowest
      MERGE(v1, v2, i1, mv1[w * 64 + tid], mv2[w * 64 + tid], mi1[w * 64 + tid]);
    int grow = r0 + tid;
    out_idx[grow] = (float)i1;
    idxi[grow] = i1;
    if (v2 - v1 < HMARGIN) {
      int p = atomicAdd(flagcount, 1);
      flagged[p] = grow;
    } else {
      used[i1] = 1;  // final winner for unflagged rows (ties always flagged)
    }
  }
}

// ---------------- exact fp32 re-rank: 1 flagged row per block, wave-per-code-slice ----------------
__global__ __launch_bounds__(256) void k_cleanup(const float* __restrict__ in,
                                                 const float* __restrict__ cb,
                                                 const float* __restrict__ cnorm,
                                                 const int* __restrict__ flagged,
                                                 const int* __restrict__ flagcount,
                                                 float* __restrict__ out_idx,
                                                 int* __restrict__ idxi,
                                                 int* __restrict__ used) {
  __shared__ unsigned long long red[4];
  int tid = threadIdx.x;
  int lane = tid & 63;
  int wave = tid >> 6;
  int nf = *flagcount;
  const float4* cb4 = (const float4*)cb;
  for (int fi = blockIdx.x; fi < nf; fi += 2048) {
    int row = flagged[fi];
    int b = row >> 12, s = row & 4095;
    const float* xp = in + b * (EMBED_DIM * SPATIAL) + s;
    float xk[4];
#pragma unroll
    for (int j = 0; j < 4; ++j) xk[j] = xp[(lane * 4 + j) * SPATIAL];
    unsigned long long best = ~0ull;
    int c0 = wave * 256;
#pragma unroll 4
    for (int cc = 0; cc < 256; ++cc) {
      int code = c0 + cc;
      float4 cv = cb4[code * 64 + lane];  // coalesced: 64 lanes x 16B
      float p = cv.x * xk[0] + cv.y * xk[1] + cv.z * xk[2] + cv.w * xk[3];
#pragma unroll
      for (int off = 1; off < 64; off <<= 1) p += __shfl_xor(p, off);
      float sc = cnorm[code] - 2.0f * p;
      unsigned long long k = ((unsigned long long)fkey(sc) << 32) | (unsigned)code;
      best = k < best ? k : best;
    }
    if (lane == 0) red[wave] = best;
    __syncthreads();
    if (tid == 0) {
      unsigned long long bb = red[0];
#pragma unroll
      for (int w = 1; w < 4; ++w) { unsigned long long o = red[w]; bb = o < bb ? o : bb; }
      int idx = (int)(bb & 0xffffffffull);
      out_idx[row] = (float)idx;
      idxi[row] = idx;
      used[idx] = 1;
    }
    __syncthreads();
  }
}

// ---------------- gather embed + MSE, transpose-tile (coalesced cb reads) ----------------
__global__ __launch_bounds__(256) void k_gather(const float* __restrict__ in,
                                                const float* __restrict__ cb,
                                                const int* __restrict__ idxi,
                                                float* __restrict__ embed_out,
                                                double* __restrict__ partials) {
  __shared__ float E[64][257];  // ~66 KB, pad -> conflict-light transposed reads
  __shared__ int idx_l[64];
  __shared__ float wsum[4];
  int tid = threadIdx.x;
  int lane = tid & 63;
  int wave = tid >> 6;
  int r0 = blockIdx.x << 6;  // 64 spatial positions (same batch)
  int b = r0 >> 12;
  int s0 = r0 & 4095;
  if (tid < 64) idx_l[tid] = idxi[r0 + tid];
  __syncthreads();
  const float4* cb4 = (const float4*)cb;
#pragma unroll
  for (int jj = 0; jj < 16; ++jj) {
    int j = wave * 16 + jj;
    float4 v = cb4[idx_l[j] * 64 + lane];
    E[j][lane * 4 + 0] = v.x;
    E[j][lane * 4 + 1] = v.y;
    E[j][lane * 4 + 2] = v.z;
    E[j][lane * 4 + 3] = v.w;
  }
  __syncthreads();
  float lsum = 0.f;
  int dbase = wave * 64;
  const float* inp = in + (b * EMBED_DIM + dbase) * SPATIAL + s0;
  float* outp = embed_out + (b * EMBED_DIM + dbase) * SPATIAL + s0;
#pragma unroll 8
  for (int dd = 0; dd < 64; ++dd) {
    float e = E[lane][dbase + dd];
    float x = inp[dd * SPATIAL + lane];
    outp[dd * SPATIAL + lane] = e;
    float df = e - x;
    lsum += df * df;
  }
#pragma unroll
  for (int off = 1; off < 64; off <<= 1) lsum += __shfl_xor(lsum, off, 64);
  if (lane == 0) wsum[wave] = lsum;
  __syncthreads();
  if (tid == 0)
    partials[blockIdx.x] = (double)(wsum[0] + wsum[1] + wsum[2] + wsum[3]);
}

// ---------------- tail: loss scalar + new_last_used ----------------
__global__ __launch_bounds__(256) void k_tail(const double* __restrict__ partials,
                                              const int* __restrict__ used,
                                              const int* __restrict__ last_used,
                                              float* __restrict__ out_loss,
                                              float* __restrict__ out_lu) {
  int tid = threadIdx.x;
  double s = 0.0;
  for (int i = tid; i < 1024; i += 256) s += partials[i];
#pragma unroll
  for (int off = 1; off < 64; off <<= 1) s += __shfl_xor(s, off, 64);
  __shared__ double sd[4];
  if ((tid & 63) == 0) sd[tid >> 6] = s;
  __syncthreads();
  if (tid == 0) {
    double total = sd[0] + sd[1] + sd[2] + sd[3];
    out_loss[0] = (float)(1.25 * total / (double)EMBED_ELEMS);
  }
  for (int i = tid; i < NUM_EMBED; i += 256)
    out_lu[i] = used[i] ? 0.0f : (float)(last_used[i] + 1);
}

extern "C" void kernel_launch(void* const* d_in, const int* in_sizes, int n_in,
                              void* d_out, int out_size, void* d_ws, size_t ws_size,
                              hipStream_t stream) {
  const float* in = (const float*)d_in[0];
  const float* cb = (const float*)d_in[1];
  const int* last_used = (const int*)d_in[2];

  float* out = (float*)d_out;
  float* out_idx = out;                       // 65536
  float* embed_out = out + NROWS;             // 16777216
  float* out_loss = embed_out + EMBED_ELEMS;  // 1
  float* out_lu = out_loss + 1;               // 1024

  _Float16* cb16 = (_Float16*)d_ws;                            // 512 KB (permuted)
  double* partials = (double*)(cb16 + NUM_EMBED * EMBED_DIM);  // 1024 double (+pad)
  int* flagged = (int*)(partials + 4096);                      // 65536 int
  int* flagcount = flagged + NROWS;                            // 16 int
  int* idxi = flagcount + 16;                                  // 65536 int
  int* used = idxi + NROWS;                                    // 1024 int
  float* cnorm = (float*)(used + NUM_EMBED);                   // 1024 float

  hipLaunchKernelGGL(k_init, dim3(193), dim3(256), 0, stream, cb, used, flagcount, cnorm, cb16);
  hipLaunchKernelGGL(k_score, dim3(1024), dim3(256), 0, stream, in, cb16, cnorm, out_idx,
                     idxi, flagged, flagcount, used);
  hipLaunchKernelGGL(k_cleanup, dim3(2048), dim3(256), 0, stream, in, cb, cnorm, flagged,
                     flagcount, out_idx, idxi, used);
  hipLaunchKernelGGL(k_gather, dim3(1024), dim3(256), 0, stream, in, cb, idxi, embed_out,
                     partials);
  hipLaunchKernelGGL(k_tail, dim3(1), dim3(256), 0, stream, partials, used, last_used,
                     out_loss, out_lu);
}

// Round 13
// 150.433 us; speedup vs baseline: 1.4854x; 1.0338x over previous
//
#include <hip/hip_runtime.h>

#define NUM_EMBED 1024
#define EMBED_DIM 256
#define SPATIAL 4096          // 64*64
#define NROWS 65536           // 16*4096
#define EMBED_ELEMS 16777216  // 16*256*4096
#define HMARGIN 0.05f         // margin on h = d2/2 scores (== 0.1 on d2)

typedef _Float16 half8 __attribute__((ext_vector_type(8)));
typedef float f32x4 __attribute__((ext_vector_type(4)));

__device__ __forceinline__ unsigned fkey(float f) {
  unsigned u = __float_as_uint(f);
  return (u & 0x80000000u) ? ~u : (u | 0x80000000u);
}

__device__ __forceinline__ void gll16(const _Float16* g, void* l) {
  __builtin_amdgcn_global_load_lds((const __attribute__((address_space(1))) void*)g,
                                   (__attribute__((address_space(3))) void*)l, 16, 0, 0);
}

#define UPD(V1, V2, I1, S, I)                            \
  { float _s = (S);                                      \
    if (_s < (V1)) { (V2) = (V1); (V1) = _s; (I1) = (I); } \
    else if (_s < (V2)) { (V2) = _s; } }

#define MERGE(V1A, V2A, I1A, V1B, V2B, I1B)                       \
  { if ((V1B) < (V1A)) { (V2A) = fminf((V1A), (V2B)); (V1A) = (V1B); (I1A) = (I1B); } \
    else { (V2A) = fminf((V2A), (V1B)); } }

// ---------------- init: used, flagcount, cnorm, cb16 (PERMUTED, 16-code chunks) ----------------
// cb16p[ch*4096 + ks*512 + lane*8 + q] = cb[(ch*16 + (lane&15))*256 + ks*32 + (lane>>4)*8 + q]
__global__ __launch_bounds__(256) void k_init(const float* __restrict__ cb,
                                              int* __restrict__ used,
                                              int* __restrict__ flagcount,
                                              float* __restrict__ cnorm,
                                              _Float16* __restrict__ cb16) {
  int bid = blockIdx.x, tid = threadIdx.x;
  if (bid == 0) {
    used[tid] = 0; used[tid + 256] = 0; used[tid + 512] = 0; used[tid + 768] = 0;
    if (tid == 0) *flagcount = 0;
  } else if (bid <= 64) {
    int c = (bid - 1) * 16 + (tid >> 4);
    int l = tid & 15;
    const float4* p = (const float4*)(cb + c * EMBED_DIM + l * 16);
    float s = 0.f;
#pragma unroll
    for (int j = 0; j < 4; ++j) {
      float4 v = p[j];
      s += v.x * v.x + v.y * v.y + v.z * v.z + v.w * v.w;
    }
#pragma unroll
    for (int off = 1; off < 16; off <<= 1) s += __shfl_xor(s, off, 16);
    if (l == 0) cnorm[c] = s;
  } else {
    int gid = (bid - 65) * 256 + tid;  // 0..32767
    int ch = gid >> 9;                 // 64 chunks of 16 codes
    int rem = gid & 511;
    int ks = rem >> 6;
    int lg = (rem >> 4) & 3;
    int ln = rem & 15;
    int S = (ch * 16 + ln) * 256 + ks * 32 + lg * 8;
    const float4* src = (const float4*)(cb + S);
    float4 a = src[0], b = src[1];
    half8 h;
    h[0] = (_Float16)a.x; h[1] = (_Float16)a.y; h[2] = (_Float16)a.z; h[3] = (_Float16)a.w;
    h[4] = (_Float16)b.x; h[5] = (_Float16)b.y; h[6] = (_Float16)b.z; h[7] = (_Float16)b.w;
    *(half8*)(cb16 + gid * 8) = h;
  }
}

// ---------------- fp16 MFMA screening: CODE-PARTITIONED, BARRIER-FREE main loop ----------------
__global__ __launch_bounds__(256, 2) void k_score(const float* __restrict__ in,
                                                  const _Float16* __restrict__ cb16,
                                                  const float* __restrict__ cnorm,
                                                  float* __restrict__ out_idx,
                                                  int* __restrict__ idxi,
                                                  int* __restrict__ flagged,
                                                  int* __restrict__ flagcount,
                                                  int* __restrict__ used) {
  __shared__ _Float16 As[8][4096];  // 64 KB: wave w owns 16 KB (2 x 8 KB ring); also X scratch
  __shared__ float cn_lds[1024];    // 4 KB, pre-scaled x0.5
  int tid = threadIdx.x;
  int lane = tid & 63;
  int wave = tid >> 6;
  int ln = lane & 15;
  int lg = lane >> 4;
  int r0 = blockIdx.x << 6;  // 64 rows/block
  const float* Ain = in + ((r0 >> 12) * (EMBED_DIM * SPATIAL)) + (r0 & 4095);

  // ---- block-wide X transpose into first 32 KB: [kc 0..31][row 0..63] 16B ----
  {
    char* scratch = (char*)As[0];
    int row = tid & 63;
    int kq = tid >> 6;
    const float* p0 = Ain + row;
#pragma unroll
    for (int j = 0; j < 8; ++j) {
      int kc = kq * 8 + j;
      half8 hv;
#pragma unroll
      for (int q = 0; q < 8; ++q) hv[q] = (_Float16)p0[(kc * 8 + q) * SPATIAL];
      *(half8*)(scratch + kc * 1024 + row * 16) = hv;
    }
#pragma unroll
    for (int i = 0; i < 4; ++i) cn_lds[tid + 256 * i] = 0.5f * cnorm[tid + 256 * i];
  }
  __syncthreads();
  half8 xf[8][4];  // 128 VGPR: all 64 rows x K=256
  {
    const char* scratch = (const char*)As[0];
#pragma unroll
    for (int ks = 0; ks < 8; ++ks)
#pragma unroll
      for (int nf = 0; nf < 4; ++nf)
        xf[ks][nf] = *(const half8*)(scratch + (ks * 4 + lg) * 1024 + (nf * 16 + ln) * 16);
  }
  __syncthreads();  // scratch free for the rings

  // per-wave ring + permuted source base (wave w -> chunks 16w..16w+15)
  char* ring = (char*)As[0] + wave * 16384;
  const _Float16* src0 = cb16 + wave * 65536 + lane * 8;

  // prologue: stage chunk 0 -> ring buf 0 (8 gll16 = 8 KB per wave)
#pragma unroll
  for (int i = 0; i < 8; ++i) gll16(src0 + i * 512, ring + i * 1024 + lane * 16);

  float sv1[4] = {3e38f, 3e38f, 3e38f, 3e38f};
  float sv2[4] = {3e38f, 3e38f, 3e38f, 3e38f};
  int si1[4] = {0, 0, 0, 0};
  int afo = lg * 256 + ln * 16;

#pragma unroll 1
  for (int c = 0; c < 16; ++c) {
    if (c < 15) {  // issue stage(c+1) into the other buffer, then counted wait
      char* dst = ring + ((c + 1) & 1) * 8192;
      const _Float16* ps = src0 + (c + 1) * 4096;
#pragma unroll
      for (int i = 0; i < 8; ++i) gll16(ps + i * 512, dst + i * 1024 + lane * 16);
      asm volatile("s_waitcnt vmcnt(8)" ::: "memory");  // chunk c landed; c+1 in flight
    } else {
      asm volatile("s_waitcnt vmcnt(0)" ::: "memory");
    }
    __builtin_amdgcn_sched_barrier(0);  // rule #18: keep ds_reads below the wait
    const char* Ac = ring + (c & 1) * 8192;
    f32x4 acc[4] = {};
    __builtin_amdgcn_s_setprio(1);
#pragma unroll
    for (int ks = 0; ks < 8; ++ks) {
      half8 af = *(const half8*)(Ac + ks * 1024 + afo);
#pragma unroll
      for (int nf = 0; nf < 4; ++nf)
        acc[nf] = __builtin_amdgcn_mfma_f32_16x16x32_f16(af, xf[ks][nf], acc[nf], 0, 0, 0);
    }
    __builtin_amdgcn_s_setprio(0);
    // fold: h = 0.5*|c|^2 - x.c ; codes cb0 + lg*4 + r, rows nf*16+ln
    int cb0 = wave * 256 + c * 16;
    float cna[4];
    *(float4*)cna = *(const float4*)(cn_lds + cb0 + lg * 4);
    int ib0 = cb0 + lg * 4;
#pragma unroll
    for (int nf = 0; nf < 4; ++nf) {
      float v1a = cna[0] - acc[nf][0], v2a = 3e38f;
      int i1a = ib0;
#pragma unroll
      for (int r = 1; r < 4; ++r) UPD(v1a, v2a, i1a, cna[r] - acc[nf][r], ib0 + r);
      MERGE(sv1[nf], sv2[nf], si1[nf], v1a, v2a, i1a);
    }
  }

  // ---- merge the 4 lane-groups (same rows, disjoint codes within the wave) ----
#pragma unroll
  for (int nf = 0; nf < 4; ++nf) {
#pragma unroll
    for (int off = 16; off < 64; off <<= 1) {
      float ov1 = __shfl_xor(sv1[nf], off);
      float ov2 = __shfl_xor(sv2[nf], off);
      int oi = __shfl_xor(si1[nf], off);
      if (ov1 < sv1[nf]) { sv2[nf] = fminf(sv1[nf], ov2); sv1[nf] = ov1; si1[nf] = oi; }
      else { sv2[nf] = fminf(sv2[nf], ov1); }
    }
  }

  // ---- cross-wave merge: waves hold disjoint code quarters of the SAME rows ----
  __syncthreads();  // all waves done with rings
  float* mv1 = (float*)As[0];       // 256 f
  float* mv2 = mv1 + 256;
  int* mi1 = (int*)(mv2 + 256);
  if (lg == 0) {
#pragma unroll
    for (int nf = 0; nf < 4; ++nf) {
      int slot = wave * 64 + nf * 16 + ln;
      mv1[slot] = sv1[nf]; mv2[slot] = sv2[nf]; mi1[slot] = si1[nf];
    }
  }
  __syncthreads();
  if (tid < 64) {
    float v1 = mv1[tid], v2 = mv2[tid];
    int i1 = mi1[tid];
#pragma unroll
    for (int w = 1; w < 4; ++w)  // ascending code ranges: ties keep lowest
      MERGE(v1, v2, i1, mv1[w * 64 + tid], mv2[w * 64 + tid], mi1[w * 64 + tid]);
    int grow = r0 + tid;
    out_idx[grow] = (float)i1;
    idxi[grow] = i1;
    if (v2 - v1 < HMARGIN) {
      int p = atomicAdd(flagcount, 1);
      flagged[p] = grow;
    } else {
      used[i1] = 1;  // final winner for unflagged rows (ties always flagged)
    }
  }
}

// ---------------- exact fp32 re-rank: 4 flagged rows/block, 16 indep accs/thread ----------------
// Thread t owns codes {t, t+256, t+512, t+768} x 4 rows; no per-code cross-lane
// reduce (the R12 killer). One packed-u64 wave reduce per row at the end.
__global__ __launch_bounds__(256) void k_cleanup(const float* __restrict__ in,
                                                 const float* __restrict__ cb,
                                                 const float* __restrict__ cnorm,
                                                 const int* __restrict__ flagged,
                                                 const int* __restrict__ flagcount,
                                                 float* __restrict__ out_idx,
                                                 int* __restrict__ idxi,
                                                 int* __restrict__ used) {
  __shared__ float xs[4][256];
  __shared__ unsigned long long red[4][4];  // [wave][row]
  int tid = threadIdx.x;
  int lane = tid & 63;
  int wave = tid >> 6;
  int nf = *flagcount;
  const float4* cb4 = (const float4*)cb;
  for (int g = blockIdx.x; g * 4 < nf; g += 2048) {
    int base = g * 4;
    int cnt = nf - base; if (cnt > 4) cnt = 4;
    {  // stage 4 rows (clamped): row j = tid>>6, k = (tid&63)*4 ..+3
      int j = tid >> 6;
      int k0 = (tid & 63) * 4;
      int fi = base + j;
      int row = flagged[fi < nf ? fi : base];
      int b = row >> 12, s = row & 4095;
      const float* p = in + b * (EMBED_DIM * SPATIAL) + s;
#pragma unroll
      for (int q = 0; q < 4; ++q) xs[j][k0 + q] = p[(k0 + q) * SPATIAL];
    }
    __syncthreads();
    float acc[4][4] = {};  // [code_i][row]
    for (int k4 = 0; k4 < 64; ++k4) {
      float4 cw[4];
#pragma unroll
      for (int i = 0; i < 4; ++i) cw[i] = cb4[(tid + 256 * i) * 64 + k4];
#pragma unroll
      for (int r = 0; r < 4; ++r) {
        float4 xv = *(const float4*)&xs[r][k4 * 4];
#pragma unroll
        for (int i = 0; i < 4; ++i)
          acc[i][r] += cw[i].x * xv.x + cw[i].y * xv.y + cw[i].z * xv.z + cw[i].w * xv.w;
      }
    }
    float cnl[4];
#pragma unroll
    for (int i = 0; i < 4; ++i) cnl[i] = cnorm[tid + 256 * i];
#pragma unroll
    for (int r = 0; r < 4; ++r) {
      unsigned long long b = ~0ull;
#pragma unroll
      for (int i = 0; i < 4; ++i) {
        float s = cnl[i] - 2.0f * acc[i][r];
        unsigned long long p =
            ((unsigned long long)fkey(s) << 32) | (unsigned)(tid + 256 * i);
        b = p < b ? p : b;
      }
#pragma unroll
      for (int off = 1; off < 64; off <<= 1) {
        unsigned long long o = __shfl_xor(b, off);
        b = o < b ? o : b;
      }
      if (lane == 0) red[wave][r] = b;
    }
    __syncthreads();
    if (tid < cnt) {
      unsigned long long b = red[0][tid];
#pragma unroll
      for (int w = 1; w < 4; ++w) { unsigned long long o = red[w][tid]; b = o < b ? o : b; }
      int row = flagged[base + tid];
      int idx = (int)(b & 0xffffffffull);
      out_idx[row] = (float)idx;
      idxi[row] = idx;
      used[idx] = 1;
    }
    __syncthreads();
  }
}

// ---------------- gather embed + MSE, transpose-tile (coalesced cb reads) ----------------
__global__ __launch_bounds__(256) void k_gather(const float* __restrict__ in,
                                                const float* __restrict__ cb,
                                                const int* __restrict__ idxi,
                                                float* __restrict__ embed_out,
                                                double* __restrict__ partials) {
  __shared__ float E[64][257];  // ~66 KB, pad -> conflict-light transposed reads
  __shared__ int idx_l[64];
  __shared__ float wsum[4];
  int tid = threadIdx.x;
  int lane = tid & 63;
  int wave = tid >> 6;
  int r0 = blockIdx.x << 6;  // 64 spatial positions (same batch)
  int b = r0 >> 12;
  int s0 = r0 & 4095;
  if (tid < 64) idx_l[tid] = idxi[r0 + tid];
  __syncthreads();
  const float4* cb4 = (const float4*)cb;
#pragma unroll
  for (int jj = 0; jj < 16; ++jj) {
    int j = wave * 16 + jj;
    float4 v = cb4[idx_l[j] * 64 + lane];
    E[j][lane * 4 + 0] = v.x;
    E[j][lane * 4 + 1] = v.y;
    E[j][lane * 4 + 2] = v.z;
    E[j][lane * 4 + 3] = v.w;
  }
  __syncthreads();
  float lsum = 0.f;
  int dbase = wave * 64;
  const float* inp = in + (b * EMBED_DIM + dbase) * SPATIAL + s0;
  float* outp = embed_out + (b * EMBED_DIM + dbase) * SPATIAL + s0;
#pragma unroll 8
  for (int dd = 0; dd < 64; ++dd) {
    float e = E[lane][dbase + dd];
    float x = inp[dd * SPATIAL + lane];
    outp[dd * SPATIAL + lane] = e;
    float df = e - x;
    lsum += df * df;
  }
#pragma unroll
  for (int off = 1; off < 64; off <<= 1) lsum += __shfl_xor(lsum, off, 64);
  if (lane == 0) wsum[wave] = lsum;
  __syncthreads();
  if (tid == 0)
    partials[blockIdx.x] = (double)(wsum[0] + wsum[1] + wsum[2] + wsum[3]);
}

// ---------------- tail: loss scalar + new_last_used ----------------
__global__ __launch_bounds__(256) void k_tail(const double* __restrict__ partials,
                                              const int* __restrict__ used,
                                              const int* __restrict__ last_used,
                                              float* __restrict__ out_loss,
                                              float* __restrict__ out_lu) {
  int tid = threadIdx.x;
  double s = 0.0;
  for (int i = tid; i < 1024; i += 256) s += partials[i];
#pragma unroll
  for (int off = 1; off < 64; off <<= 1) s += __shfl_xor(s, off, 64);
  __shared__ double sd[4];
  if ((tid & 63) == 0) sd[tid >> 6] = s;
  __syncthreads();
  if (tid == 0) {
    double total = sd[0] + sd[1] + sd[2] + sd[3];
    out_loss[0] = (float)(1.25 * total / (double)EMBED_ELEMS);
  }
  for (int i = tid; i < NUM_EMBED; i += 256)
    out_lu[i] = used[i] ? 0.0f : (float)(last_used[i] + 1);
}

extern "C" void kernel_launch(void* const* d_in, const int* in_sizes, int n_in,
                              void* d_out, int out_size, void* d_ws, size_t ws_size,
                              hipStream_t stream) {
  const float* in = (const float*)d_in[0];
  const float* cb = (const float*)d_in[1];
  const int* last_used = (const int*)d_in[2];

  float* out = (float*)d_out;
  float* out_idx = out;                       // 65536
  float* embed_out = out + NROWS;             // 16777216
  float* out_loss = embed_out + EMBED_ELEMS;  // 1
  float* out_lu = out_loss + 1;               // 1024

  _Float16* cb16 = (_Float16*)d_ws;                            // 512 KB (permuted)
  double* partials = (double*)(cb16 + NUM_EMBED * EMBED_DIM);  // 1024 double (+pad)
  int* flagged = (int*)(partials + 4096);                      // 65536 int
  int* flagcount = flagged + NROWS;                            // 16 int
  int* idxi = flagcount + 16;                                  // 65536 int
  int* used = idxi + NROWS;                                    // 1024 int
  float* cnorm = (float*)(used + NUM_EMBED);                   // 1024 float

  hipLaunchKernelGGL(k_init, dim3(193), dim3(256), 0, stream, cb, used, flagcount, cnorm, cb16);
  hipLaunchKernelGGL(k_score, dim3(1024), dim3(256), 0, stream, in, cb16, cnorm, out_idx,
                     idxi, flagged, flagcount, used);
  hipLaunchKernelGGL(k_cleanup, dim3(2048), dim3(256), 0, stream, in, cb, cnorm, flagged,
                     flagcount, out_idx, idxi, used);
  hipLaunchKernelGGL(k_gather, dim3(1024), dim3(256), 0, stream, in, cb, idxi, embed_out,
                     partials);
  hipLaunchKernelGGL(k_tail, dim3(1), dim3(256), 0, stream, partials, used, last_used,
                     out_loss, out_lu);
}

// Round 14
// 136.006 us; speedup vs baseline: 1.6429x; 1.1061x over previous
//
#include <hip/hip_runtime.h>

#define NUM_EMBED 1024
#define EMBED_DIM 256
#define SPATIAL 4096          // 64*64
#define NROWS 65536           // 16*4096
#define EMBED_ELEMS 16777216  // 16*256*4096
#define HMARGIN 0.05f         // margin on h = d2/2 scores (== 0.1 on d2)

typedef _Float16 half8 __attribute__((ext_vector_type(8)));
typedef float f32x4 __attribute__((ext_vector_type(4)));

__device__ __forceinline__ unsigned fkey(float f) {
  unsigned u = __float_as_uint(f);
  return (u & 0x80000000u) ? ~u : (u | 0x80000000u);
}

__device__ __forceinline__ void gll16(const _Float16* g, void* l) {
  __builtin_amdgcn_global_load_lds((const __attribute__((address_space(1))) void*)g,
                                   (__attribute__((address_space(3))) void*)l, 16, 0, 0);
}

#define UPD(V1, V2, I1, S, I)                            \
  { float _s = (S);                                      \
    if (_s < (V1)) { (V2) = (V1); (V1) = _s; (I1) = (I); } \
    else if (_s < (V2)) { (V2) = _s; } }

#define MERGE(V1A, V2A, I1A, V1B, V2B, I1B)                       \
  { if ((V1B) < (V1A)) { (V2A) = fminf((V1A), (V2B)); (V1A) = (V1B); (I1A) = (I1B); } \
    else { (V2A) = fminf((V2A), (V1B)); } }

// ---------------- init: used, flagcount, cnorm, cb16 (PERMUTED, 16-code chunks) ----------------
// cb16p[ch*4096 + ks*512 + lane*8 + q] = cb[(ch*16 + (lane&15))*256 + ks*32 + (lane>>4)*8 + q]
__global__ __launch_bounds__(256) void k_init(const float* __restrict__ cb,
                                              int* __restrict__ used,
                                              int* __restrict__ flagcount,
                                              float* __restrict__ cnorm,
                                              _Float16* __restrict__ cb16) {
  int bid = blockIdx.x, tid = threadIdx.x;
  if (bid == 0) {
    used[tid] = 0; used[tid + 256] = 0; used[tid + 512] = 0; used[tid + 768] = 0;
    if (tid == 0) *flagcount = 0;
  } else if (bid <= 64) {
    int c = (bid - 1) * 16 + (tid >> 4);
    int l = tid & 15;
    const float4* p = (const float4*)(cb + c * EMBED_DIM + l * 16);
    float s = 0.f;
#pragma unroll
    for (int j = 0; j < 4; ++j) {
      float4 v = p[j];
      s += v.x * v.x + v.y * v.y + v.z * v.z + v.w * v.w;
    }
#pragma unroll
    for (int off = 1; off < 16; off <<= 1) s += __shfl_xor(s, off, 16);
    if (l == 0) cnorm[c] = s;
  } else {
    int gid = (bid - 65) * 256 + tid;  // 0..32767
    int ch = gid >> 9;                 // 64 chunks of 16 codes
    int rem = gid & 511;
    int ks = rem >> 6;
    int lg = (rem >> 4) & 3;
    int ln = rem & 15;
    int S = (ch * 16 + ln) * 256 + ks * 32 + lg * 8;
    const float4* src = (const float4*)(cb + S);
    float4 a = src[0], b = src[1];
    half8 h;
    h[0] = (_Float16)a.x; h[1] = (_Float16)a.y; h[2] = (_Float16)a.z; h[3] = (_Float16)a.w;
    h[4] = (_Float16)b.x; h[5] = (_Float16)b.y; h[6] = (_Float16)b.z; h[7] = (_Float16)b.w;
    *(half8*)(cb16 + gid * 8) = h;
  }
}

// ---------------- fp16 MFMA screening: CODE-PARTITIONED, BARRIER-FREE main loop ----------------
__global__ __launch_bounds__(256, 2) void k_score(const float* __restrict__ in,
                                                  const _Float16* __restrict__ cb16,
                                                  const float* __restrict__ cnorm,
                                                  float* __restrict__ out_idx,
                                                  int* __restrict__ idxi,
                                                  int* __restrict__ flagged,
                                                  int* __restrict__ flagcount,
                                                  int* __restrict__ used) {
  __shared__ _Float16 As[8][4096];  // 64 KB: wave w owns 16 KB (2 x 8 KB ring); also X scratch
  __shared__ float cn_lds[1024];    // 4 KB, pre-scaled x0.5
  int tid = threadIdx.x;
  int lane = tid & 63;
  int wave = tid >> 6;
  int ln = lane & 15;
  int lg = lane >> 4;
  int r0 = blockIdx.x << 6;  // 64 rows/block
  const float* Ain = in + ((r0 >> 12) * (EMBED_DIM * SPATIAL)) + (r0 & 4095);

  // ---- block-wide X transpose into first 32 KB: [kc 0..31][row 0..63] 16B ----
  {
    char* scratch = (char*)As[0];
    int row = tid & 63;
    int kq = tid >> 6;
    const float* p0 = Ain + row;
#pragma unroll
    for (int j = 0; j < 8; ++j) {
      int kc = kq * 8 + j;
      half8 hv;
#pragma unroll
      for (int q = 0; q < 8; ++q) hv[q] = (_Float16)p0[(kc * 8 + q) * SPATIAL];
      *(half8*)(scratch + kc * 1024 + row * 16) = hv;
    }
#pragma unroll
    for (int i = 0; i < 4; ++i) cn_lds[tid + 256 * i] = 0.5f * cnorm[tid + 256 * i];
  }
  __syncthreads();
  half8 xf[8][4];  // 128 VGPR: all 64 rows x K=256
  {
    const char* scratch = (const char*)As[0];
#pragma unroll
    for (int ks = 0; ks < 8; ++ks)
#pragma unroll
      for (int nf = 0; nf < 4; ++nf)
        xf[ks][nf] = *(const half8*)(scratch + (ks * 4 + lg) * 1024 + (nf * 16 + ln) * 16);
  }
  __syncthreads();  // scratch free for the rings

  // per-wave ring + permuted source base (wave w -> chunks 16w..16w+15)
  char* ring = (char*)As[0] + wave * 16384;
  const _Float16* src0 = cb16 + wave * 65536 + lane * 8;

  // prologue: stage chunk 0 -> ring buf 0 (8 gll16 = 8 KB per wave)
#pragma unroll
  for (int i = 0; i < 8; ++i) gll16(src0 + i * 512, ring + i * 1024 + lane * 16);

  float sv1[4] = {3e38f, 3e38f, 3e38f, 3e38f};
  float sv2[4] = {3e38f, 3e38f, 3e38f, 3e38f};
  int si1[4] = {0, 0, 0, 0};
  int afo = lg * 256 + ln * 16;

#pragma unroll 1
  for (int c = 0; c < 16; ++c) {
    if (c < 15) {  // issue stage(c+1) into the other buffer, then counted wait
      char* dst = ring + ((c + 1) & 1) * 8192;
      const _Float16* ps = src0 + (c + 1) * 4096;
#pragma unroll
      for (int i = 0; i < 8; ++i) gll16(ps + i * 512, dst + i * 1024 + lane * 16);
      asm volatile("s_waitcnt vmcnt(8)" ::: "memory");  // chunk c landed; c+1 in flight
    } else {
      asm volatile("s_waitcnt vmcnt(0)" ::: "memory");
    }
    __builtin_amdgcn_sched_barrier(0);  // rule #18: keep ds_reads below the wait
    const char* Ac = ring + (c & 1) * 8192;
    f32x4 acc[4] = {};
    __builtin_amdgcn_s_setprio(1);
#pragma unroll
    for (int ks = 0; ks < 8; ++ks) {
      half8 af = *(const half8*)(Ac + ks * 1024 + afo);
#pragma unroll
      for (int nf = 0; nf < 4; ++nf)
        acc[nf] = __builtin_amdgcn_mfma_f32_16x16x32_f16(af, xf[ks][nf], acc[nf], 0, 0, 0);
    }
    __builtin_amdgcn_s_setprio(0);
    // fold: h = 0.5*|c|^2 - x.c ; codes cb0 + lg*4 + r, rows nf*16+ln
    int cb0 = wave * 256 + c * 16;
    float cna[4];
    *(float4*)cna = *(const float4*)(cn_lds + cb0 + lg * 4);
    int ib0 = cb0 + lg * 4;
#pragma unroll
    for (int nf = 0; nf < 4; ++nf) {
      float v1a = cna[0] - acc[nf][0], v2a = 3e38f;
      int i1a = ib0;
#pragma unroll
      for (int r = 1; r < 4; ++r) UPD(v1a, v2a, i1a, cna[r] - acc[nf][r], ib0 + r);
      MERGE(sv1[nf], sv2[nf], si1[nf], v1a, v2a, i1a);
    }
  }

  // ---- merge the 4 lane-groups (same rows, disjoint codes within the wave) ----
#pragma unroll
  for (int nf = 0; nf < 4; ++nf) {
#pragma unroll
    for (int off = 16; off < 64; off <<= 1) {
      float ov1 = __shfl_xor(sv1[nf], off);
      float ov2 = __shfl_xor(sv2[nf], off);
      int oi = __shfl_xor(si1[nf], off);
      if (ov1 < sv1[nf]) { sv2[nf] = fminf(sv1[nf], ov2); sv1[nf] = ov1; si1[nf] = oi; }
      else { sv2[nf] = fminf(sv2[nf], ov1); }
    }
  }

  // ---- cross-wave merge: waves hold disjoint code quarters of the SAME rows ----
  __syncthreads();  // all waves done with rings
  float* mv1 = (float*)As[0];       // 256 f
  float* mv2 = mv1 + 256;
  int* mi1 = (int*)(mv2 + 256);
  if (lg == 0) {
#pragma unroll
    for (int nf = 0; nf < 4; ++nf) {
      int slot = wave * 64 + nf * 16 + ln;
      mv1[slot] = sv1[nf]; mv2[slot] = sv2[nf]; mi1[slot] = si1[nf];
    }
  }
  __syncthreads();
  if (tid < 64) {
    float v1 = mv1[tid], v2 = mv2[tid];
    int i1 = mi1[tid];
#pragma unroll
    for (int w = 1; w < 4; ++w)  // ascending code ranges: ties keep lowest
      MERGE(v1, v2, i1, mv1[w * 64 + tid], mv2[w * 64 + tid], mi1[w * 64 + tid]);
    int grow = r0 + tid;
    out_idx[grow] = (float)i1;
    idxi[grow] = i1;
    if (v2 - v1 < HMARGIN) {
      int p = atomicAdd(flagcount, 1);
      flagged[p] = grow;
    } else {
      used[i1] = 1;  // final winner for unflagged rows (ties always flagged)
    }
  }
}

// ---------------- exact fp32 re-rank: 1 row/block, 16-lane-per-code groups ----------------
// Wave w owns codes [256w, 256w+256) in 64 groups of 4 codes. Per group each
// 16-lane sub-group reads its code row COALESCED (4 x float4/lane), x comes from
// LDS with 4-way broadcast, 4-step intra-16 shuffle reduce. No full-wave
// butterflies, no strided cb reads.
__global__ __launch_bounds__(256) void k_cleanup(const float* __restrict__ in,
                                                 const float* __restrict__ cb,
                                                 const float* __restrict__ cnorm,
                                                 const int* __restrict__ flagged,
                                                 const int* __restrict__ flagcount,
                                                 float* __restrict__ out_idx,
                                                 int* __restrict__ idxi,
                                                 int* __restrict__ used) {
  __shared__ float xs[256];
  __shared__ unsigned long long red[4];
  int tid = threadIdx.x;
  int lane = tid & 63;
  int wave = tid >> 6;
  int sub = lane & 15;   // lane within 16-lane code group
  int cg = lane >> 4;    // which of 4 codes in the group
  int nf = *flagcount;
  const float4* cb4 = (const float4*)cb;
  for (int fi = blockIdx.x; fi < nf; fi += 2048) {
    int row = flagged[fi];
    int b = row >> 12, s = row & 4095;
    xs[tid] = in[b * (EMBED_DIM * SPATIAL) + tid * SPATIAL + s];
    __syncthreads();
    const float4* xs4 = (const float4*)xs;
    float4 x0 = xs4[sub], x1 = xs4[16 + sub], x2 = xs4[32 + sub], x3 = xs4[48 + sub];
    unsigned long long best = ~0ull;
    int c0 = wave * 256 + cg;
#pragma unroll 4
    for (int g = 0; g < 64; ++g) {
      int c = c0 + g * 4;
      const float4* crow = cb4 + c * 64 + sub;
      float4 d0 = crow[0], d1 = crow[16], d2 = crow[32], d3 = crow[48];
      float p = d0.x * x0.x + d0.y * x0.y + d0.z * x0.z + d0.w * x0.w;
      p += d1.x * x1.x + d1.y * x1.y + d1.z * x1.z + d1.w * x1.w;
      p += d2.x * x2.x + d2.y * x2.y + d2.z * x2.z + d2.w * x2.w;
      p += d3.x * x3.x + d3.y * x3.y + d3.z * x3.z + d3.w * x3.w;
#pragma unroll
      for (int off = 1; off < 16; off <<= 1) p += __shfl_xor(p, off);
      if (sub == 0) {
        float sc = cnorm[c] - 2.0f * p;
        unsigned long long k = ((unsigned long long)fkey(sc) << 32) | (unsigned)c;
        best = k < best ? k : best;
      }
    }
    // wave min over the 4 group-leader lanes (others hold ~0ull)
    {
      unsigned long long o = __shfl_xor(best, 16); best = o < best ? o : best;
      o = __shfl_xor(best, 32); best = o < best ? o : best;
    }
    if (lane == 0) red[wave] = best;
    __syncthreads();
    if (tid == 0) {
      unsigned long long bb = red[0];
#pragma unroll
      for (int w = 1; w < 4; ++w) { unsigned long long o = red[w]; bb = o < bb ? o : bb; }
      int idx = (int)(bb & 0xffffffffull);
      out_idx[row] = (float)idx;
      idxi[row] = idx;
      used[idx] = 1;
    }
    __syncthreads();
  }
}

// ---------------- gather embed + MSE, transpose-tile (coalesced cb reads) ----------------
__global__ __launch_bounds__(256) void k_gather(const float* __restrict__ in,
                                                const float* __restrict__ cb,
                                                const int* __restrict__ idxi,
                                                float* __restrict__ embed_out,
                                                double* __restrict__ partials) {
  __shared__ float E[64][257];  // ~66 KB, pad -> conflict-light transposed reads
  __shared__ int idx_l[64];
  __shared__ float wsum[4];
  int tid = threadIdx.x;
  int lane = tid & 63;
  int wave = tid >> 6;
  int r0 = blockIdx.x << 6;  // 64 spatial positions (same batch)
  int b = r0 >> 12;
  int s0 = r0 & 4095;
  if (tid < 64) idx_l[tid] = idxi[r0 + tid];
  __syncthreads();
  const float4* cb4 = (const float4*)cb;
#pragma unroll
  for (int jj = 0; jj < 16; ++jj) {
    int j = wave * 16 + jj;
    float4 v = cb4[idx_l[j] * 64 + lane];
    E[j][lane * 4 + 0] = v.x;
    E[j][lane * 4 + 1] = v.y;
    E[j][lane * 4 + 2] = v.z;
    E[j][lane * 4 + 3] = v.w;
  }
  __syncthreads();
  float lsum = 0.f;
  int dbase = wave * 64;
  const float* inp = in + (b * EMBED_DIM + dbase) * SPATIAL + s0;
  float* outp = embed_out + (b * EMBED_DIM + dbase) * SPATIAL + s0;
#pragma unroll 8
  for (int dd = 0; dd < 64; ++dd) {
    float e = E[lane][dbase + dd];
    float x = inp[dd * SPATIAL + lane];
    outp[dd * SPATIAL + lane] = e;
    float df = e - x;
    lsum += df * df;
  }
#pragma unroll
  for (int off = 1; off < 64; off <<= 1) lsum += __shfl_xor(lsum, off, 64);
  if (lane == 0) wsum[wave] = lsum;
  __syncthreads();
  if (tid == 0)
    partials[blockIdx.x] = (double)(wsum[0] + wsum[1] + wsum[2] + wsum[3]);
}

// ---------------- tail: loss scalar + new_last_used ----------------
__global__ __launch_bounds__(256) void k_tail(const double* __restrict__ partials,
                                              const int* __restrict__ used,
                                              const int* __restrict__ last_used,
                                              float* __restrict__ out_loss,
                                              float* __restrict__ out_lu) {
  int tid = threadIdx.x;
  double s = 0.0;
  for (int i = tid; i < 1024; i += 256) s += partials[i];
#pragma unroll
  for (int off = 1; off < 64; off <<= 1) s += __shfl_xor(s, off, 64);
  __shared__ double sd[4];
  if ((tid & 63) == 0) sd[tid >> 6] = s;
  __syncthreads();
  if (tid == 0) {
    double total = sd[0] + sd[1] + sd[2] + sd[3];
    out_loss[0] = (float)(1.25 * total / (double)EMBED_ELEMS);
  }
  for (int i = tid; i < NUM_EMBED; i += 256)
    out_lu[i] = used[i] ? 0.0f : (float)(last_used[i] + 1);
}

extern "C" void kernel_launch(void* const* d_in, const int* in_sizes, int n_in,
                              void* d_out, int out_size, void* d_ws, size_t ws_size,
                              hipStream_t stream) {
  const float* in = (const float*)d_in[0];
  const float* cb = (const float*)d_in[1];
  const int* last_used = (const int*)d_in[2];

  float* out = (float*)d_out;
  float* out_idx = out;                       // 65536
  float* embed_out = out + NROWS;             // 16777216
  float* out_loss = embed_out + EMBED_ELEMS;  // 1
  float* out_lu = out_loss + 1;               // 1024

  _Float16* cb16 = (_Float16*)d_ws;                            // 512 KB (permuted)
  double* partials = (double*)(cb16 + NUM_EMBED * EMBED_DIM);  // 1024 double (+pad)
  int* flagged = (int*)(partials + 4096);                      // 65536 int
  int* flagcount = flagged + NROWS;                            // 16 int
  int* idxi = flagcount + 16;                                  // 65536 int
  int* used = idxi + NROWS;                                    // 1024 int
  float* cnorm = (float*)(used + NUM_EMBED);                   // 1024 float

  hipLaunchKernelGGL(k_init, dim3(193), dim3(256), 0, stream, cb, used, flagcount, cnorm, cb16);
  hipLaunchKernelGGL(k_score, dim3(1024), dim3(256), 0, stream, in, cb16, cnorm, out_idx,
                     idxi, flagged, flagcount, used);
  hipLaunchKernelGGL(k_cleanup, dim3(2048), dim3(256), 0, stream, in, cb, cnorm, flagged,
                     flagcount, out_idx, idxi, used);
  hipLaunchKernelGGL(k_gather, dim3(1024), dim3(256), 0, stream, in, cb, idxi, embed_out,
                     partials);
  hipLaunchKernelGGL(k_tail, dim3(1), dim3(256), 0, stream, partials, used, last_used,
                     out_loss, out_lu);
}

// Round 15
// 133.394 us; speedup vs baseline: 1.6751x; 1.0196x over previous
//
#include <hip/hip_runtime.h>

#define NUM_EMBED 1024
#define EMBED_DIM 256
#define SPATIAL 4096          // 64*64
#define NROWS 65536           // 16*4096
#define EMBED_ELEMS 16777216  // 16*256*4096
#define HMARGIN 0.05f         // margin on h = d2/2 scores (== 0.1 on d2)

typedef _Float16 half8 __attribute__((ext_vector_type(8)));
typedef float f32x4 __attribute__((ext_vector_type(4)));

__device__ __forceinline__ unsigned fkey(float f) {
  unsigned u = __float_as_uint(f);
  return (u & 0x80000000u) ? ~u : (u | 0x80000000u);
}

#define UPD(V1, V2, I1, S, I)                            \
  { float _s = (S);                                      \
    if (_s < (V1)) { (V2) = (V1); (V1) = _s; (I1) = (I); } \
    else if (_s < (V2)) { (V2) = _s; } }

#define MERGE(V1A, V2A, I1A, V1B, V2B, I1B)                       \
  { if ((V1B) < (V1A)) { (V2A) = fminf((V1A), (V2B)); (V1A) = (V1B); (I1A) = (I1B); } \
    else { (V2A) = fminf((V2A), (V1B)); } }

// ---------------- init: used, flagcount, cnorm, cb16 (PERMUTED, 16-code chunks) ----------------
// cb16p[ch*4096 + ks*512 + lane*8 + q] = cb[(ch*16 + (lane&15))*256 + ks*32 + (lane>>4)*8 + q]
__global__ __launch_bounds__(256) void k_init(const float* __restrict__ cb,
                                              int* __restrict__ used,
                                              int* __restrict__ flagcount,
                                              float* __restrict__ cnorm,
                                              _Float16* __restrict__ cb16) {
  int bid = blockIdx.x, tid = threadIdx.x;
  if (bid == 0) {
    used[tid] = 0; used[tid + 256] = 0; used[tid + 512] = 0; used[tid + 768] = 0;
    if (tid == 0) *flagcount = 0;
  } else if (bid <= 64) {
    int c = (bid - 1) * 16 + (tid >> 4);
    int l = tid & 15;
    const float4* p = (const float4*)(cb + c * EMBED_DIM + l * 16);
    float s = 0.f;
#pragma unroll
    for (int j = 0; j < 4; ++j) {
      float4 v = p[j];
      s += v.x * v.x + v.y * v.y + v.z * v.z + v.w * v.w;
    }
#pragma unroll
    for (int off = 1; off < 16; off <<= 1) s += __shfl_xor(s, off, 16);
    if (l == 0) cnorm[c] = s;
  } else {
    int gid = (bid - 65) * 256 + tid;  // 0..32767
    int ch = gid >> 9;                 // 64 chunks of 16 codes
    int rem = gid & 511;
    int ks = rem >> 6;
    int lg = (rem >> 4) & 3;
    int ln = rem & 15;
    int S = (ch * 16 + ln) * 256 + ks * 32 + lg * 8;
    const float4* src = (const float4*)(cb + S);
    float4 a = src[0], b = src[1];
    half8 h;
    h[0] = (_Float16)a.x; h[1] = (_Float16)a.y; h[2] = (_Float16)a.z; h[3] = (_Float16)a.w;
    h[4] = (_Float16)b.x; h[5] = (_Float16)b.y; h[6] = (_Float16)b.z; h[7] = (_Float16)b.w;
    *(half8*)(cb16 + gid * 8) = h;
  }
}

// ---------------- fp16 MFMA screening: code-partitioned, REG-STAGED (T14) ----------------
// block: 64 rows, 4 waves; wave w screens codes [256w, 256w+256) as 16 chunks
// of 16 codes. xf[8][4] in regs. Staging: per chunk issue 8 global b128 loads
// to REGISTERS early, compute current chunk from the wave-private 8 KB LDS
// buffer, then ds_write the next chunk (compiler inserts counted vmcnt via reg
// deps). No gll16, no manual waitcnt, no barriers in the loop. LDS 36 KB.
__global__ __launch_bounds__(256, 2) void k_score(const float* __restrict__ in,
                                                  const _Float16* __restrict__ cb16,
                                                  const float* __restrict__ cnorm,
                                                  float* __restrict__ out_idx,
                                                  int* __restrict__ idxi,
                                                  int* __restrict__ flagged,
                                                  int* __restrict__ flagcount,
                                                  int* __restrict__ used) {
  __shared__ _Float16 As[4][4096];  // 32 KB: wave w owns 8 KB; also X-transpose scratch
  __shared__ float cn_lds[1024];    // 4 KB, pre-scaled x0.5
  int tid = threadIdx.x;
  int lane = tid & 63;
  int wave = tid >> 6;
  int ln = lane & 15;
  int lg = lane >> 4;
  int r0 = blockIdx.x << 6;  // 64 rows/block
  const float* Ain = in + ((r0 >> 12) * (EMBED_DIM * SPATIAL)) + (r0 & 4095);

  // ---- block-wide X transpose into the 32 KB scratch: [kc 0..31][row 0..63] 16B ----
  {
    char* scratch = (char*)As[0];
    int row = tid & 63;
    int kq = tid >> 6;
    const float* p0 = Ain + row;
#pragma unroll
    for (int j = 0; j < 8; ++j) {
      int kc = kq * 8 + j;
      half8 hv;
#pragma unroll
      for (int q = 0; q < 8; ++q) hv[q] = (_Float16)p0[(kc * 8 + q) * SPATIAL];
      *(half8*)(scratch + kc * 1024 + row * 16) = hv;
    }
#pragma unroll
    for (int i = 0; i < 4; ++i) cn_lds[tid + 256 * i] = 0.5f * cnorm[tid + 256 * i];
  }
  __syncthreads();
  half8 xf[8][4];  // all 64 rows x K=256
  {
    const char* scratch = (const char*)As[0];
#pragma unroll
    for (int ks = 0; ks < 8; ++ks)
#pragma unroll
      for (int nf = 0; nf < 4; ++nf)
        xf[ks][nf] = *(const half8*)(scratch + (ks * 4 + lg) * 1024 + (nf * 16 + ln) * 16);
  }
  __syncthreads();  // scratch free for the per-wave buffers

  // wave-private 8 KB buffer + permuted source base (wave w -> chunks 16w..16w+15)
  char* buf = (char*)As[0] + wave * 8192;
  const _Float16* src0 = cb16 + wave * 65536 + lane * 8;

  // prologue: chunk 0 -> regs -> LDS
  half8 stg[8];
#pragma unroll
  for (int i = 0; i < 8; ++i) stg[i] = *(const half8*)(src0 + i * 512);
#pragma unroll
  for (int i = 0; i < 8; ++i) *(half8*)(buf + i * 1024 + lane * 16) = stg[i];

  float sv1[4] = {3e38f, 3e38f, 3e38f, 3e38f};
  float sv2[4] = {3e38f, 3e38f, 3e38f, 3e38f};
  int si1[4] = {0, 0, 0, 0};
  int afo = lg * 256 + ln * 16;

#pragma unroll 1
  for (int c = 0; c < 16; ++c) {
    // issue next chunk's loads EARLY (latency hides under this chunk's compute)
    if (c < 15) {
      const _Float16* ps = src0 + (c + 1) * 4096;
#pragma unroll
      for (int i = 0; i < 8; ++i) stg[i] = *(const half8*)(ps + i * 512);
    }
    // compute chunk c from the LDS buffer
    f32x4 acc[4] = {};
    __builtin_amdgcn_s_setprio(1);
#pragma unroll
    for (int ks = 0; ks < 8; ++ks) {
      half8 af = *(const half8*)(buf + ks * 1024 + afo);
#pragma unroll
      for (int nf = 0; nf < 4; ++nf)
        acc[nf] = __builtin_amdgcn_mfma_f32_16x16x32_f16(af, xf[ks][nf], acc[nf], 0, 0, 0);
    }
    __builtin_amdgcn_s_setprio(0);
    // fold: h = 0.5*|c|^2 - x.c ; codes cb0 + lg*4 + r, rows nf*16+ln
    int cb0 = wave * 256 + c * 16;
    float cna[4];
    *(float4*)cna = *(const float4*)(cn_lds + cb0 + lg * 4);
    int ib0 = cb0 + lg * 4;
#pragma unroll
    for (int nf = 0; nf < 4; ++nf) {
      float v1a = cna[0] - acc[nf][0], v2a = 3e38f;
      int i1a = ib0;
#pragma unroll
      for (int r = 1; r < 4; ++r) UPD(v1a, v2a, i1a, cna[r] - acc[nf][r], ib0 + r);
      MERGE(sv1[nf], sv2[nf], si1[nf], v1a, v2a, i1a);
    }
    // write next chunk into the buffer (reads of chunk c above already done;
    // same-wave LDS ordering + reg data-deps give the counted vmcnt for free)
    if (c < 15) {
#pragma unroll
      for (int i = 0; i < 8; ++i) *(half8*)(buf + i * 1024 + lane * 16) = stg[i];
    }
  }

  // ---- merge the 4 lane-groups (same rows, disjoint codes within the wave) ----
#pragma unroll
  for (int nf = 0; nf < 4; ++nf) {
#pragma unroll
    for (int off = 16; off < 64; off <<= 1) {
      float ov1 = __shfl_xor(sv1[nf], off);
      float ov2 = __shfl_xor(sv2[nf], off);
      int oi = __shfl_xor(si1[nf], off);
      if (ov1 < sv1[nf]) { sv2[nf] = fminf(sv1[nf], ov2); sv1[nf] = ov1; si1[nf] = oi; }
      else { sv2[nf] = fminf(sv2[nf], ov1); }
    }
  }

  // ---- cross-wave merge: waves hold disjoint code quarters of the SAME rows ----
  __syncthreads();  // all waves done with buffers
  float* mv1 = (float*)As[0];  // 256 f
  float* mv2 = mv1 + 256;
  int* mi1 = (int*)(mv2 + 256);
  if (lg == 0) {
#pragma unroll
    for (int nf = 0; nf < 4; ++nf) {
      int slot = wave * 64 + nf * 16 + ln;
      mv1[slot] = sv1[nf]; mv2[slot] = sv2[nf]; mi1[slot] = si1[nf];
    }
  }
  __syncthreads();
  if (tid < 64) {
    float v1 = mv1[tid], v2 = mv2[tid];
    int i1 = mi1[tid];
#pragma unroll
    for (int w = 1; w < 4; ++w)  // ascending code ranges: ties keep lowest
      MERGE(v1, v2, i1, mv1[w * 64 + tid], mv2[w * 64 + tid], mi1[w * 64 + tid]);
    int grow = r0 + tid;
    out_idx[grow] = (float)i1;
    idxi[grow] = i1;
    if (v2 - v1 < HMARGIN) {
      int p = atomicAdd(flagcount, 1);
      flagged[p] = grow;
    } else {
      used[i1] = 1;  // final winner for unflagged rows (ties always flagged)
    }
  }
}

// ---------------- exact fp32 re-rank: 1 row/block, 16-lane-per-code groups ----------------
__global__ __launch_bounds__(256) void k_cleanup(const float* __restrict__ in,
                                                 const float* __restrict__ cb,
                                                 const float* __restrict__ cnorm,
                                                 const int* __restrict__ flagged,
                                                 const int* __restrict__ flagcount,
                                                 float* __restrict__ out_idx,
                                                 int* __restrict__ idxi,
                                                 int* __restrict__ used) {
  __shared__ float xs[256];
  __shared__ unsigned long long red[4];
  int tid = threadIdx.x;
  int lane = tid & 63;
  int wave = tid >> 6;
  int sub = lane & 15;
  int cg = lane >> 4;
  int nf = *flagcount;
  const float4* cb4 = (const float4*)cb;
  for (int fi = blockIdx.x; fi < nf; fi += 2048) {
    int row = flagged[fi];
    int b = row >> 12, s = row & 4095;
    xs[tid] = in[b * (EMBED_DIM * SPATIAL) + tid * SPATIAL + s];
    __syncthreads();
    const float4* xs4 = (const float4*)xs;
    float4 x0 = xs4[sub], x1 = xs4[16 + sub], x2 = xs4[32 + sub], x3 = xs4[48 + sub];
    unsigned long long best = ~0ull;
    int c0 = wave * 256 + cg;
#pragma unroll 4
    for (int g = 0; g < 64; ++g) {
      int c = c0 + g * 4;
      const float4* crow = cb4 + c * 64 + sub;
      float4 d0 = crow[0], d1 = crow[16], d2 = crow[32], d3 = crow[48];
      float p = d0.x * x0.x + d0.y * x0.y + d0.z * x0.z + d0.w * x0.w;
      p += d1.x * x1.x + d1.y * x1.y + d1.z * x1.z + d1.w * x1.w;
      p += d2.x * x2.x + d2.y * x2.y + d2.z * x2.z + d2.w * x2.w;
      p += d3.x * x3.x + d3.y * x3.y + d3.z * x3.z + d3.w * x3.w;
#pragma unroll
      for (int off = 1; off < 16; off <<= 1) p += __shfl_xor(p, off);
      if (sub == 0) {
        float sc = cnorm[c] - 2.0f * p;
        unsigned long long k = ((unsigned long long)fkey(sc) << 32) | (unsigned)c;
        best = k < best ? k : best;
      }
    }
    {
      unsigned long long o = __shfl_xor(best, 16); best = o < best ? o : best;
      o = __shfl_xor(best, 32); best = o < best ? o : best;
    }
    if (lane == 0) red[wave] = best;
    __syncthreads();
    if (tid == 0) {
      unsigned long long bb = red[0];
#pragma unroll
      for (int w = 1; w < 4; ++w) { unsigned long long o = red[w]; bb = o < bb ? o : bb; }
      int idx = (int)(bb & 0xffffffffull);
      out_idx[row] = (float)idx;
      idxi[row] = idx;
      used[idx] = 1;
    }
    __syncthreads();
  }
}

// ---------------- gather embed + MSE, 32-position tiles (4 blocks/CU) ----------------
__global__ __launch_bounds__(256) void k_gather(const float* __restrict__ in,
                                                const float* __restrict__ cb,
                                                const int* __restrict__ idxi,
                                                float* __restrict__ embed_out,
                                                double* __restrict__ partials) {
  __shared__ float E[32][257];  // ~33 KB
  __shared__ int idx_l[32];
  __shared__ float wsum[4];
  int tid = threadIdx.x;
  int lane = tid & 63;
  int wave = tid >> 6;
  int r0 = blockIdx.x << 5;  // 32 spatial positions (same batch)
  int b = r0 >> 12;
  int s0 = r0 & 4095;
  if (tid < 32) idx_l[tid] = idxi[r0 + tid];
  __syncthreads();
  const float4* cb4 = (const float4*)cb;
#pragma unroll
  for (int jj = 0; jj < 8; ++jj) {
    int j = wave * 8 + jj;
    float4 v = cb4[idx_l[j] * 64 + lane];
    E[j][lane * 4 + 0] = v.x;
    E[j][lane * 4 + 1] = v.y;
    E[j][lane * 4 + 2] = v.z;
    E[j][lane * 4 + 3] = v.w;
  }
  __syncthreads();
  float lsum = 0.f;
  int s = lane & 31;
  int dpar = lane >> 5;  // wave covers 2 d per instruction
  const float* inp = in + b * (EMBED_DIM * SPATIAL) + s0 + s;
  float* outp = embed_out + b * (EMBED_DIM * SPATIAL) + s0 + s;
#pragma unroll 8
  for (int i = 0; i < 32; ++i) {
    int d = wave * 64 + i * 2 + dpar;
    float e = E[s][d];
    float x = inp[d * SPATIAL];
    outp[d * SPATIAL] = e;
    float df = e - x;
    lsum += df * df;
  }
#pragma unroll
  for (int off = 1; off < 64; off <<= 1) lsum += __shfl_xor(lsum, off, 64);
  if (lane == 0) wsum[wave] = lsum;
  __syncthreads();
  if (tid == 0)
    partials[blockIdx.x] = (double)(wsum[0] + wsum[1] + wsum[2] + wsum[3]);
}

// ---------------- tail: loss scalar + new_last_used ----------------
__global__ __launch_bounds__(256) void k_tail(const double* __restrict__ partials,
                                              const int* __restrict__ used,
                                              const int* __restrict__ last_used,
                                              float* __restrict__ out_loss,
                                              float* __restrict__ out_lu) {
  int tid = threadIdx.x;
  double s = 0.0;
  for (int i = tid; i < 2048; i += 256) s += partials[i];
#pragma unroll
  for (int off = 1; off < 64; off <<= 1) s += __shfl_xor(s, off, 64);
  __shared__ double sd[4];
  if ((tid & 63) == 0) sd[tid >> 6] = s;
  __syncthreads();
  if (tid == 0) {
    double total = sd[0] + sd[1] + sd[2] + sd[3];
    out_loss[0] = (float)(1.25 * total / (double)EMBED_ELEMS);
  }
  for (int i = tid; i < NUM_EMBED; i += 256)
    out_lu[i] = used[i] ? 0.0f : (float)(last_used[i] + 1);
}

extern "C" void kernel_launch(void* const* d_in, const int* in_sizes, int n_in,
                              void* d_out, int out_size, void* d_ws, size_t ws_size,
                              hipStream_t stream) {
  const float* in = (const float*)d_in[0];
  const float* cb = (const float*)d_in[1];
  const int* last_used = (const int*)d_in[2];

  float* out = (float*)d_out;
  float* out_idx = out;                       // 65536
  float* embed_out = out + NROWS;             // 16777216
  float* out_loss = embed_out + EMBED_ELEMS;  // 1
  float* out_lu = out_loss + 1;               // 1024

  _Float16* cb16 = (_Float16*)d_ws;                            // 512 KB (permuted)
  double* partials = (double*)(cb16 + NUM_EMBED * EMBED_DIM);  // 2048 double (+pad)
  int* flagged = (int*)(partials + 4096);                      // 65536 int
  int* flagcount = flagged + NROWS;                            // 16 int
  int* idxi = flagcount + 16;                                  // 65536 int
  int* used = idxi + NROWS;                                    // 1024 int
  float* cnorm = (float*)(used + NUM_EMBED);                   // 1024 float

  hipLaunchKernelGGL(k_init, dim3(193), dim3(256), 0, stream, cb, used, flagcount, cnorm, cb16);
  hipLaunchKernelGGL(k_score, dim3(1024), dim3(256), 0, stream, in, cb16, cnorm, out_idx,
                     idxi, flagged, flagcount, used);
  hipLaunchKernelGGL(k_cleanup, dim3(2048), dim3(256), 0, stream, in, cb, cnorm, flagged,
                     flagcount, out_idx, idxi, used);
  hipLaunchKernelGGL(k_gather, dim3(2048), dim3(256), 0, stream, in, cb, idxi, embed_out,
                     partials);
  hipLaunchKernelGGL(k_tail, dim3(1), dim3(256), 0, stream, partials, used, last_used,
                     out_loss, out_lu);
}